// Round 11
// baseline (905.459 us; speedup 1.0000x reference)
//
#include <hip/hip_runtime.h>
#include <hip/hip_bf16.h>
#include <math.h>

#define SLEN 4096
#define CIN 256
#define C3 768
#define NH 4
#define HD 64
#define BATCH 4

typedef __attribute__((ext_vector_type(8))) short bf16x8;
typedef __attribute__((ext_vector_type(4))) float f32x4;
typedef __attribute__((ext_vector_type(16))) float f32x16;

typedef const __attribute__((address_space(1))) void GVoid;
typedef __attribute__((address_space(3))) void LVoid;

__device__ __forceinline__ void gl2lds16(const void* g, void* l) {
    __builtin_amdgcn_global_load_lds((GVoid*)g, (LVoid*)l, 16, 0, 0);
}

__device__ __forceinline__ short f2bf(float f) {
    union { float f; unsigned u; } v; v.f = f;
    unsigned r = v.u + 0x7fff + ((v.u >> 16) & 1);
    return (short)(r >> 16);
}

// single-instruction packed f32->bf16 (RNE) — no builtin on gfx950, inline asm per T12
__device__ __forceinline__ unsigned cvt_pk(float lo, float hi) {
    unsigned r;
    asm("v_cvt_pk_bf16_f32 %0, %1, %2" : "=v"(r) : "v"(lo), "v"(hi));
    return r;
}

// ---------------- kernel W: convert weights to bf16 ----------------
__global__ void k_convert_w(const float* __restrict__ qkvw, const float* __restrict__ projw,
                            short* __restrict__ qkvw_bf, short* __restrict__ projw_bf) {
    int i = blockIdx.x * 256 + threadIdx.x;
    if (i < C3 * CIN) qkvw_bf[i] = f2bf(qkvw[i]);
    if (i < CIN * CIN) projw_bf[i] = f2bf(projw[i]);
}

// ---------------- kernel A: fused transpose + QKV GEMM + BN + SiLU ----------------
// Reads x [b][c][s] fp32 directly (coalesced float4), stages 32k x 128s chunks as f32
// in LDS, assembles bf16 A-fragments via transposed ds_read_b32 + v_cvt_pk_bf16_f32.
// Q,K: [bh][s][d]; Vt: [bh][d][s]. Q pre-scaled by hd^-0.5 * log2(e).
__launch_bounds__(256)
__global__ void k_qkv(const float* __restrict__ x, const short* __restrict__ wbf,
                      const float* __restrict__ g, const float* __restrict__ be,
                      const float* __restrict__ mu, const float* __restrict__ va,
                      short* __restrict__ Q, short* __restrict__ Kb, short* __restrict__ Vt) {
    __shared__ __align__(16) float xt[32][136];   // [k-chunk][s], pad 136 keeps 16B rows
    int wv = threadIdx.x >> 6, l = threadIdx.x & 63, lr = l & 15, lg = l >> 4;
    int b = blockIdx.z;
    int sblk = blockIdx.x * 128;
    int s0 = sblk + wv * 32;
    int o0 = blockIdx.y * 64;

    // staging geometry: thread covers row c = tid>>3, 4 float4 segments
    int tc = threadIdx.x >> 3;
    int tg = threadIdx.x & 7;
    const float* xsrc = x + ((size_t)b * CIN + tc) * SLEN + sblk + tg * 4;

    f32x4 acc[2][4] = {};
    const short* bptr = wbf + (size_t)(o0 + lr) * CIN + lg * 8;
    const float* xrd0 = &xt[lg * 8][wv * 32 + 0 * 16 + lr];
    const float* xrd1 = &xt[lg * 8][wv * 32 + 1 * 16 + lr];

#pragma unroll
    for (int ch = 0; ch < 8; ++ch) {
        int k0 = ch * 32;
        __syncthreads();
        // stage chunk: x[b][k0 + tc][sblk .. sblk+127] -> xt[tc][s]
        const float* xs = xsrc + (size_t)k0 * SLEN;
#pragma unroll
        for (int j = 0; j < 4; ++j) {
            float4 v = *reinterpret_cast<const float4*>(xs + j * 32);
            *reinterpret_cast<float4*>(&xt[tc][tg * 4 + j * 32]) = v;
        }
        __syncthreads();

        // A-fragments: transposed reads + cvt_pk
        union { bf16x8 v; unsigned u[4]; } a0, a1;
#pragma unroll
        for (int p = 0; p < 4; ++p) {
            a0.u[p] = cvt_pk(xrd0[(2 * p) * 136], xrd0[(2 * p + 1) * 136]);
            a1.u[p] = cvt_pk(xrd1[(2 * p) * 136], xrd1[(2 * p + 1) * 136]);
        }
#pragma unroll
        for (int oj = 0; oj < 4; oj++) {
            bf16x8 bb = *(const bf16x8*)(bptr + oj * 16 * CIN + k0);
            acc[0][oj] = __builtin_amdgcn_mfma_f32_16x16x32_bf16(a0.v, bb, acc[0][oj], 0, 0, 0);
            acc[1][oj] = __builtin_amdgcn_mfma_f32_16x16x32_bf16(a1.v, bb, acc[1][oj], 0, 0, 0);
        }
    }

    int which = o0 >> 8;          // uniform per block
    int h = (o0 & 255) >> 6;      // uniform per block
    int bh = b * NH + h;
    const float QSC = 0.125f * 1.44269504088896f;
#pragma unroll
    for (int oj = 0; oj < 4; oj++) {
        int o = o0 + oj * 16 + lr;
        float sc = g[o] * rsqrtf(va[o] + 1e-5f);
        float sh = be[o] - mu[o] * sc;
        int d = o & 63;
#pragma unroll
        for (int qi = 0; qi < 2; qi++) {
#pragma unroll
            for (int i = 0; i < 4; i++) {
                float y = acc[qi][oj][i] * sc + sh;
                float z = y / (1.f + __expf(-y));
                int s = s0 + qi * 16 + lg * 4 + i;
                if (which == 0) {
                    Q[((size_t)bh * SLEN + s) * HD + d] = f2bf(z * QSC);
                } else if (which == 1) {
                    Kb[((size_t)bh * SLEN + s) * HD + d] = f2bf(z);
                } else {
                    Vt[((size_t)bh * HD + d) * SLEN + s] = f2bf(z);
                }
            }
        }
    }
}

// ---------------- kernel ATTN: flash attention, split-KV x2 ----------------
// 1024 blocks = 16 bh x 32 qblk x 2 kvh; 4 waves/block, 32 q/wave, 32 KV-tiles/block.
// K 2-buf @ lds+0, V 3-buf @ lds+16384 (40960 B -> exactly 4 blocks/CU, 16 waves/CU).
// Staging via global_load_lds w/ pre-swizzled source; 6-phase unrolled steady loop
// (K mod2 x V mod3 x Sset mod2 all literal). Outputs UNNORMALIZED fp32 partials +
// (m, sum) per q; k_merge combines the two kv-halves.
__launch_bounds__(256, 4)
__global__ void k_attn(const short* __restrict__ Q, const short* __restrict__ Kg,
                       const short* __restrict__ Vg,
                       float* __restrict__ Opart, float2* __restrict__ mlbuf) {
    __shared__ __align__(16) char lds[16384 + 24576];
    int tid = threadIdx.x;
    int wv = tid >> 6, l = tid & 63;
    int q32 = l & 31;
    int hi  = l >> 5;

    // XCD-aware decode: xcd owns bh {2k,2k+1}; both kv-halves stay on the same XCD
    int bid = blockIdx.x;
    int xcd = bid & 7, slot = bid >> 3;
    int bh = 2 * xcd + (slot & 1);
    int rem = slot >> 1;          // 0..63
    int qblk = rem >> 1;          // 0..31
    int kvh = rem & 1;
    int q0 = qblk * 128 + wv * 32;

    const short* kg = Kg + (size_t)bh * SLEN * HD;
    const short* vg = Vg + (size_t)bh * HD * SLEN;

    bf16x8 qf[4];
    {
        const short* qb = Q + ((size_t)bh * SLEN + q0 + q32) * HD + hi * 8;
        qf[0] = *(const bf16x8*)(qb);
        qf[1] = *(const bf16x8*)(qb + 16);
        qf[2] = *(const bf16x8*)(qb + 32);
        qf[3] = *(const bf16x8*)(qb + 48);
    }

    bf16x8 ones;
#pragma unroll
    for (int e = 0; e < 8; ++e) ones[e] = (short)0x3F80;

    f32x16 oacc0 = {}, oacc1 = {}, sacc = {};
    float mrun = 0.0f, bA = 0.0f, bB = 0.0f;

    int colsw = (((l & 7) ^ (l >> 3)) << 4);
    const char* kgB = (const char*)kg + (size_t)kvh * 32 * 8192;
    const char* vgB = (const char*)vg + (size_t)kvh * 32 * 128;
    int ksrc = (wv * 16 + (l >> 3)) * 128 + colsw;
    int vsrc = (wv * 16 + (l >> 3)) * 8192 + colsw;
    int wdst = wv * 2048;

#define STAGE(T, KB, VB) do { \
    gl2lds16(kgB + (size_t)(T) * 8192 + ksrc,          lds + (KB) * 8192 + wdst); \
    gl2lds16(kgB + (size_t)(T) * 8192 + ksrc + 1024,   lds + (KB) * 8192 + wdst + 1024); \
    gl2lds16(vgB + (size_t)(T) * 128 + vsrc,           lds + 16384 + (VB) * 8192 + wdst); \
    gl2lds16(vgB + (size_t)(T) * 128 + vsrc + 65536,   lds + 16384 + (VB) * 8192 + wdst + 1024); \
} while (0)

#define VMBAR() do { \
    asm volatile("s_waitcnt vmcnt(0) lgkmcnt(0)" ::: "memory"); \
    __builtin_amdgcn_s_barrier(); \
    asm volatile("" ::: "memory"); \
} while (0)

    int swz = (l & 7) << 4;
    int a0 = q32 * 128 + ((0 * 32 + hi * 16) ^ swz);
    int a1 = q32 * 128 + ((1 * 32 + hi * 16) ^ swz);
    int a2 = q32 * 128 + ((2 * 32 + hi * 16) ^ swz);
    int a3 = q32 * 128 + ((3 * 32 + hi * 16) ^ swz);

#define QKT(KB, D0, D1, BSET) do { \
    BSET = mrun; \
    float nb_ = -mrun; \
    _Pragma("unroll") for (int r_ = 0; r_ < 16; ++r_) { D0[r_] = nb_; D1[r_] = nb_; } \
    __builtin_amdgcn_s_setprio(1); \
    { \
        bf16x8 k0_, k1_; \
        k0_ = *(const bf16x8*)(lds + a0 + (KB) * 8192); \
        k1_ = *(const bf16x8*)(lds + a0 + (KB) * 8192 + 4096); \
        D0 = __builtin_amdgcn_mfma_f32_32x32x16_bf16(k0_, qf[0], D0, 0, 0, 0); \
        D1 = __builtin_amdgcn_mfma_f32_32x32x16_bf16(k1_, qf[0], D1, 0, 0, 0); \
        k0_ = *(const bf16x8*)(lds + a1 + (KB) * 8192); \
        k1_ = *(const bf16x8*)(lds + a1 + (KB) * 8192 + 4096); \
        D0 = __builtin_amdgcn_mfma_f32_32x32x16_bf16(k0_, qf[1], D0, 0, 0, 0); \
        D1 = __builtin_amdgcn_mfma_f32_32x32x16_bf16(k1_, qf[1], D1, 0, 0, 0); \
        k0_ = *(const bf16x8*)(lds + a2 + (KB) * 8192); \
        k1_ = *(const bf16x8*)(lds + a2 + (KB) * 8192 + 4096); \
        D0 = __builtin_amdgcn_mfma_f32_32x32x16_bf16(k0_, qf[2], D0, 0, 0, 0); \
        D1 = __builtin_amdgcn_mfma_f32_32x32x16_bf16(k1_, qf[2], D1, 0, 0, 0); \
        k0_ = *(const bf16x8*)(lds + a3 + (KB) * 8192); \
        k1_ = *(const bf16x8*)(lds + a3 + (KB) * 8192 + 4096); \
        D0 = __builtin_amdgcn_mfma_f32_32x32x16_bf16(k0_, qf[3], D0, 0, 0, 0); \
        D1 = __builtin_amdgcn_mfma_f32_32x32x16_bf16(k1_, qf[3], D1, 0, 0, 0); \
    } \
    __builtin_amdgcn_s_setprio(0); \
} while (0)

#define PVKC(AK, SV, BASE, VB) do { \
    unsigned A0_ = cvt_pk(SV[(BASE) + 0], SV[(BASE) + 1]); \
    unsigned A1_ = cvt_pk(SV[(BASE) + 2], SV[(BASE) + 3]); \
    unsigned A2_ = cvt_pk(SV[(BASE) + 4], SV[(BASE) + 5]); \
    unsigned A3_ = cvt_pk(SV[(BASE) + 6], SV[(BASE) + 7]); \
    asm volatile("v_permlane32_swap_b32 %0, %1" : "+v"(A0_), "+v"(A2_)); \
    asm volatile("v_permlane32_swap_b32 %0, %1" : "+v"(A1_), "+v"(A3_)); \
    union { bf16x8 v; unsigned u[4]; } pf_; \
    pf_.u[0] = A0_; pf_.u[1] = A1_; pf_.u[2] = A2_; pf_.u[3] = A3_; \
    bf16x8 v0_ = *(const bf16x8*)(lds + (AK) + 16384 + (VB) * 8192); \
    bf16x8 v1_ = *(const bf16x8*)(lds + (AK) + 16384 + (VB) * 8192 + 4096); \
    oacc0 = __builtin_amdgcn_mfma_f32_32x32x16_bf16(v0_, pf_.v, oacc0, 0, 0, 0); \
    oacc1 = __builtin_amdgcn_mfma_f32_32x32x16_bf16(v1_, pf_.v, oacc1, 0, 0, 0); \
    sacc  = __builtin_amdgcn_mfma_f32_32x32x16_bf16(ones, pf_.v, sacc, 0, 0, 0); \
} while (0)

#define SMPV(VB, S0, S1, BSET) do { \
    float pa_ = S0[0], pb_ = S0[8], pc_ = S1[0], pd_ = S1[8]; \
    _Pragma("unroll") for (int r_ = 1; r_ < 8; ++r_) { \
        pa_ = fmaxf(pa_, S0[r_]); pb_ = fmaxf(pb_, S0[8 + r_]); \
        pc_ = fmaxf(pc_, S1[r_]); pd_ = fmaxf(pd_, S1[8 + r_]); \
    } \
    float pms_ = fmaxf(fmaxf(pa_, pb_), fmaxf(pc_, pd_)); \
    float c1_ = pms_, c2_ = pms_; \
    asm volatile("" : "+v"(c2_)); /* force distinct register */ \
    asm volatile("v_permlane32_swap_b32 %0, %1" : "+v"(c1_), "+v"(c2_)); \
    pms_ = fmaxf(c1_, c2_); \
    float db_ = mrun - (BSET); \
    if (!__all(pms_ <= db_ + 10.0f)) { \
        float mn_ = fmaxf(mrun, pms_ + (BSET)); \
        float al_ = __builtin_amdgcn_exp2f(mrun - mn_); \
        _Pragma("unroll") for (int r_ = 0; r_ < 16; ++r_) { oacc0[r_] *= al_; oacc1[r_] *= al_; } \
        sacc[0] *= al_; \
        mrun = mn_; db_ = mn_ - (BSET); \
    } \
    if (__all(db_ == 0.0f)) { \
        _Pragma("unroll") for (int r_ = 0; r_ < 16; ++r_) { \
            S0[r_] = __builtin_amdgcn_exp2f(S0[r_]); \
            S1[r_] = __builtin_amdgcn_exp2f(S1[r_]); \
        } \
    } else { \
        _Pragma("unroll") for (int r_ = 0; r_ < 16; ++r_) { \
            S0[r_] = __builtin_amdgcn_exp2f(S0[r_] - db_); \
            S1[r_] = __builtin_amdgcn_exp2f(S1[r_] - db_); \
        } \
    } \
    __builtin_amdgcn_s_setprio(1); \
    PVKC(a0, S0, 0, VB); \
    PVKC(a1, S0, 8, VB); \
    PVKC(a2, S1, 0, VB); \
    PVKC(a3, S1, 8, VB); \
    __builtin_amdgcn_s_setprio(0); \
} while (0)

    f32x16 sA0, sA1, sB0, sB1;

    // prologue: stage 0; drain; stage 1 + QK(0)->A; drain
    STAGE(0, 0, 0);
    VMBAR();
    STAGE(1, 1, 1);
    QKT(0, sA0, sA1, bA);
    VMBAR();

    // steady state: t = 1..30, 6-phase unroll (K mod2, V mod3, S-set mod2 literal)
    for (int m = 0; m < 5; ++m) {
        STAGE(6 * m + 2, 0, 2); QKT(1, sB0, sB1, bB); SMPV(0, sA0, sA1, bA); VMBAR();
        STAGE(6 * m + 3, 1, 0); QKT(0, sA0, sA1, bA); SMPV(1, sB0, sB1, bB); VMBAR();
        STAGE(6 * m + 4, 0, 1); QKT(1, sB0, sB1, bB); SMPV(2, sA0, sA1, bA); VMBAR();
        STAGE(6 * m + 5, 1, 2); QKT(0, sA0, sA1, bA); SMPV(0, sB0, sB1, bB); VMBAR();
        STAGE(6 * m + 6, 0, 0); QKT(1, sB0, sB1, bB); SMPV(1, sA0, sA1, bA); VMBAR();
        STAGE(6 * m + 7, 1, 1); QKT(0, sA0, sA1, bA); SMPV(2, sB0, sB1, bB); VMBAR();
    }
    // t = 31: QKT(31)->B, finish tile 30 (A, V buf 30%3=0); then finish 31 (B, V 31%3=1)
    QKT(1, sB0, sB1, bB); SMPV(0, sA0, sA1, bA);
    SMPV(1, sB0, sB1, bB);

    // ---- epilogue: store UNNORMALIZED fp32 partial O^T + (m, sum) per q ----
    size_t p = ((size_t)(bh * 32 + qblk) * 2 + kvh);
    int ql = wv * 32 + q32;
    float* op = Opart + (p * 128 + ql) * 64;
#pragma unroll
    for (int g4 = 0; g4 < 4; ++g4) {
        float4 s0 = make_float4(oacc0[4 * g4 + 0], oacc0[4 * g4 + 1],
                                oacc0[4 * g4 + 2], oacc0[4 * g4 + 3]);
        float4 s1 = make_float4(oacc1[4 * g4 + 0], oacc1[4 * g4 + 1],
                                oacc1[4 * g4 + 2], oacc1[4 * g4 + 3]);
        *reinterpret_cast<float4*>(op + 8 * g4 + 4 * hi) = s0;
        *reinterpret_cast<float4*>(op + 32 + 8 * g4 + 4 * hi) = s1;
    }
    if (hi == 0) {
        float2 mlv; mlv.x = mrun; mlv.y = sacc[0];
        mlbuf[p * 128 + ql] = mlv;
    }
#undef STAGE
#undef VMBAR
#undef QKT
#undef PVKC
#undef SMPV
}

// ---------------- kernel M: merge the two kv-half partials -> aout bf16 ----------------
__launch_bounds__(256)
__global__ void k_merge(const float* __restrict__ Opart, const float2* __restrict__ mlbuf,
                        short* __restrict__ aout) {
    int bq = blockIdx.x;              // bh*32 + qblk
    int bh = bq >> 5, qblk = bq & 31;
    int tid = threadIdx.x;
    int dq = tid & 15;                // float4 index within 64-d row
    int qb = tid >> 4;                // 0..15
    size_t p1 = (size_t)bq * 2, p2 = p1 + 1;
    const float4* O1 = (const float4*)(Opart + p1 * 128 * 64);
    const float4* O2 = (const float4*)(Opart + p2 * 128 * 64);
    const float2* ml1 = mlbuf + p1 * 128;
    const float2* ml2 = mlbuf + p2 * 128;
    int b = bh >> 2, h = bh & 3;
    short* ob = aout + ((size_t)b * SLEN + qblk * 128) * CIN + h * HD;
#pragma unroll
    for (int j = 0; j < 8; ++j) {
        int ql = qb + 16 * j;
        float2 a = ml1[ql], c = ml2[ql];
        float mstar = fmaxf(a.x, c.x);
        float w1 = __builtin_amdgcn_exp2f(a.x - mstar);
        float w2 = __builtin_amdgcn_exp2f(c.x - mstar);
        float inv = 1.f / (a.y * w1 + c.y * w2);
        float4 o1 = O1[ql * 16 + dq];
        float4 o2 = O2[ql * 16 + dq];
        uint2 st;
        st.x = cvt_pk((o1.x * w1 + o2.x * w2) * inv, (o1.y * w1 + o2.y * w2) * inv);
        st.y = cvt_pk((o1.z * w1 + o2.z * w2) * inv, (o1.w * w1 + o2.w * w2) * inv);
        *reinterpret_cast<uint2*>(ob + (size_t)ql * CIN + dq * 4) = st;
    }
}

// ---------------- kernel C: proj GEMM + BN + SiLU -> fp32 out ----------------
__launch_bounds__(256)
__global__ void k_proj(const short* __restrict__ aout, const short* __restrict__ wbf,
                       const float* __restrict__ g, const float* __restrict__ be,
                       const float* __restrict__ mu, const float* __restrict__ va,
                       float* __restrict__ out) {
    int wv = threadIdx.x >> 6, l = threadIdx.x & 63, lr = l & 15, lg = l >> 4;
    int b = blockIdx.z;
    int s0 = blockIdx.x * 128 + wv * 32;
    int o0 = blockIdx.y * 64;
    f32x4 acc[2][4] = {};
    const short* aptr = aout + ((size_t)b * SLEN + s0 + lr) * CIN + lg * 8;
    const short* bptr = wbf + (size_t)(o0 + lr) * CIN + lg * 8;
#pragma unroll
    for (int k0 = 0; k0 < CIN; k0 += 32) {
        bf16x8 a0 = *(const bf16x8*)(aptr + k0);
        bf16x8 a1 = *(const bf16x8*)(aptr + 16 * CIN + k0);
#pragma unroll
        for (int oj = 0; oj < 4; oj++) {
            bf16x8 bb = *(const bf16x8*)(bptr + oj * 16 * CIN + k0);
            acc[0][oj] = __builtin_amdgcn_mfma_f32_16x16x32_bf16(a0, bb, acc[0][oj], 0, 0, 0);
            acc[1][oj] = __builtin_amdgcn_mfma_f32_16x16x32_bf16(a1, bb, acc[1][oj], 0, 0, 0);
        }
    }
#pragma unroll
    for (int oj = 0; oj < 4; oj++) {
        int o = o0 + oj * 16 + lr;
        float sc = g[o] * rsqrtf(va[o] + 1e-5f);
        float sh = be[o] - mu[o] * sc;
#pragma unroll
        for (int qi = 0; qi < 2; qi++) {
            float4 st;
            float* stp = &st.x;
#pragma unroll
            for (int i = 0; i < 4; i++) {
                float y = acc[qi][oj][i] * sc + sh;
                stp[i] = y / (1.f + __expf(-y));
            }
            int s = s0 + qi * 16 + lg * 4;
            *reinterpret_cast<float4*>(out + ((size_t)b * CIN + o) * SLEN + s) = st;
        }
    }
}

extern "C" void kernel_launch(void* const* d_in, const int* in_sizes, int n_in,
                              void* d_out, int out_size, void* d_ws, size_t ws_size,
                              hipStream_t stream) {
    const float* x    = (const float*)d_in[0];
    const float* qkvw = (const float*)d_in[1];
    const float* qg   = (const float*)d_in[2];
    const float* qbe  = (const float*)d_in[3];
    const float* qmu  = (const float*)d_in[4];
    const float* qva  = (const float*)d_in[5];
    const float* pw   = (const float*)d_in[6];
    const float* pg   = (const float*)d_in[7];
    const float* pbe  = (const float*)d_in[8];
    const float* pmu  = (const float*)d_in[9];
    const float* pva  = (const float*)d_in[10];
    float* out = (float*)d_out;

    char* ws = (char*)d_ws;
    short* qkvw_bf  = (short*)(ws);                 //    393,216 B
    short* projw_bf = (short*)(ws + 393216);        //    131,072 B
    short* Qb       = (short*)(ws + 524288);        //  8,388,608 B
    short* Kb       = (short*)(ws + 8912896);       //  8,388,608 B
    short* Vt       = (short*)(ws + 17301504);      //  8,388,608 B
    short* aout     = (short*)(ws + 25690112);      //  8,388,608 B
    float* Opart    = (float*)(ws + 34078720);      // 33,554,432 B
    float2* mlbuf   = (float2*)(ws + 67633152);     //  1,048,576 B

    k_convert_w<<<768, 256, 0, stream>>>(qkvw, pw, qkvw_bf, projw_bf);
    k_qkv<<<dim3(32, 12, 4), 256, 0, stream>>>(x, qkvw_bf, qg, qbe, qmu, qva, Qb, Kb, Vt);
    k_attn<<<1024, 256, 0, stream>>>(Qb, Kb, Vt, Opart, mlbuf);
    k_merge<<<512, 256, 0, stream>>>(Opart, mlbuf, aout);
    k_proj<<<dim3(32, 4, 4), 256, 0, stream>>>(aout, projw_bf, pg, pbe, pmu, pva, out);
}

// Round 12
// 167.801 us; speedup vs baseline: 5.3960x; 5.3960x over previous
//
#include <hip/hip_runtime.h>
#include <hip/hip_bf16.h>
#include <math.h>

#define SLEN 4096
#define CIN 256
#define C3 768
#define NH 4
#define HD 64
#define BATCH 4

typedef __attribute__((ext_vector_type(8))) short bf16x8;
typedef __attribute__((ext_vector_type(4))) float f32x4;
typedef __attribute__((ext_vector_type(16))) float f32x16;

typedef const __attribute__((address_space(1))) void GVoid;
typedef __attribute__((address_space(3))) void LVoid;

__device__ __forceinline__ void gl2lds16(const void* g, void* l) {
    __builtin_amdgcn_global_load_lds((GVoid*)g, (LVoid*)l, 16, 0, 0);
}

__device__ __forceinline__ short f2bf(float f) {
    union { float f; unsigned u; } v; v.f = f;
    unsigned r = v.u + 0x7fff + ((v.u >> 16) & 1);
    return (short)(r >> 16);
}

// single-instruction packed f32->bf16 (RNE) — no builtin on gfx950, inline asm per T12
__device__ __forceinline__ unsigned cvt_pk(float lo, float hi) {
    unsigned r;
    asm("v_cvt_pk_bf16_f32 %0, %1, %2" : "=v"(r) : "v"(lo), "v"(hi));
    return r;
}

// ---------------- kernel W: convert weights to bf16 ----------------
__global__ void k_convert_w(const float* __restrict__ qkvw, const float* __restrict__ projw,
                            short* __restrict__ qkvw_bf, short* __restrict__ projw_bf) {
    int i = blockIdx.x * 256 + threadIdx.x;
    if (i < C3 * CIN) qkvw_bf[i] = f2bf(qkvw[i]);
    if (i < CIN * CIN) projw_bf[i] = f2bf(projw[i]);
}

// ---------------- kernel A: fused transpose + QKV GEMM + BN + SiLU ----------------
// Reads x [b][c][s] fp32 directly (coalesced float4), stages 32k x 128s chunks as f32
// in LDS, assembles bf16 A-fragments via transposed ds_read_b32 + v_cvt_pk_bf16_f32.
// Q,K: [bh][s][d]; Vt: [bh][d][s]. Q pre-scaled by hd^-0.5 * log2(e).
__launch_bounds__(256)
__global__ void k_qkv(const float* __restrict__ x, const short* __restrict__ wbf,
                      const float* __restrict__ g, const float* __restrict__ be,
                      const float* __restrict__ mu, const float* __restrict__ va,
                      short* __restrict__ Q, short* __restrict__ Kb, short* __restrict__ Vt) {
    __shared__ __align__(16) float xt[32][136];   // [k-chunk][s], pad 136 keeps 16B rows
    int wv = threadIdx.x >> 6, l = threadIdx.x & 63, lr = l & 15, lg = l >> 4;
    int b = blockIdx.z;
    int sblk = blockIdx.x * 128;
    int s0 = sblk + wv * 32;
    int o0 = blockIdx.y * 64;

    // staging geometry: thread covers row c = tid>>3, 4 float4 segments
    int tc = threadIdx.x >> 3;
    int tg = threadIdx.x & 7;
    const float* xsrc = x + ((size_t)b * CIN + tc) * SLEN + sblk + tg * 4;

    f32x4 acc[2][4] = {};
    const short* bptr = wbf + (size_t)(o0 + lr) * CIN + lg * 8;
    const float* xrd0 = &xt[lg * 8][wv * 32 + 0 * 16 + lr];
    const float* xrd1 = &xt[lg * 8][wv * 32 + 1 * 16 + lr];

#pragma unroll
    for (int ch = 0; ch < 8; ++ch) {
        int k0 = ch * 32;
        __syncthreads();
        // stage chunk: x[b][k0 + tc][sblk .. sblk+127] -> xt[tc][s]
        const float* xs = xsrc + (size_t)k0 * SLEN;
#pragma unroll
        for (int j = 0; j < 4; ++j) {
            float4 v = *reinterpret_cast<const float4*>(xs + j * 32);
            *reinterpret_cast<float4*>(&xt[tc][tg * 4 + j * 32]) = v;
        }
        __syncthreads();

        // A-fragments: transposed reads + cvt_pk
        union { bf16x8 v; unsigned u[4]; } a0, a1;
#pragma unroll
        for (int p = 0; p < 4; ++p) {
            a0.u[p] = cvt_pk(xrd0[(2 * p) * 136], xrd0[(2 * p + 1) * 136]);
            a1.u[p] = cvt_pk(xrd1[(2 * p) * 136], xrd1[(2 * p + 1) * 136]);
        }
#pragma unroll
        for (int oj = 0; oj < 4; oj++) {
            bf16x8 bb = *(const bf16x8*)(bptr + oj * 16 * CIN + k0);
            acc[0][oj] = __builtin_amdgcn_mfma_f32_16x16x32_bf16(a0.v, bb, acc[0][oj], 0, 0, 0);
            acc[1][oj] = __builtin_amdgcn_mfma_f32_16x16x32_bf16(a1.v, bb, acc[1][oj], 0, 0, 0);
        }
    }

    int which = o0 >> 8;          // uniform per block
    int h = (o0 & 255) >> 6;      // uniform per block
    int bh = b * NH + h;
    const float QSC = 0.125f * 1.44269504088896f;
#pragma unroll
    for (int oj = 0; oj < 4; oj++) {
        int o = o0 + oj * 16 + lr;
        float sc = g[o] * rsqrtf(va[o] + 1e-5f);
        float sh = be[o] - mu[o] * sc;
        int d = o & 63;
#pragma unroll
        for (int qi = 0; qi < 2; qi++) {
#pragma unroll
            for (int i = 0; i < 4; i++) {
                float y = acc[qi][oj][i] * sc + sh;
                float z = y / (1.f + __expf(-y));
                int s = s0 + qi * 16 + lg * 4 + i;
                if (which == 0) {
                    Q[((size_t)bh * SLEN + s) * HD + d] = f2bf(z * QSC);
                } else if (which == 1) {
                    Kb[((size_t)bh * SLEN + s) * HD + d] = f2bf(z);
                } else {
                    Vt[((size_t)bh * HD + d) * SLEN + s] = f2bf(z);
                }
            }
        }
    }
}

// ---------------- kernel ATTN: flash attention, split-KV x2, occupancy-first ----
// 1024 blocks = 16 bh x 32 qblk x 2 kvh; 4 waves/block, 32 q/wave, 32 KV-tiles/block.
// SINGLE score set (sequential QKT->SMPV per tile) + VALU row-sum -> small register
// state so HW can run 4 blocks/CU. K 2-buf @ lds+0, V 2-buf @ lds+16384 (32768 B),
// stage exactly ONE tile ahead (race-free with sequential use). Unnormalized fp32
// partials + (m,sum); k_merge combines the two kv-halves.
__launch_bounds__(256)
__global__ void k_attn(const short* __restrict__ Q, const short* __restrict__ Kg,
                       const short* __restrict__ Vg,
                       float* __restrict__ Opart, float2* __restrict__ mlbuf) {
    __shared__ __align__(16) char lds[16384 + 16384];
    int tid = threadIdx.x;
    int wv = tid >> 6, l = tid & 63;
    int q32 = l & 31;
    int hi  = l >> 5;

    // XCD-aware decode: xcd owns bh {2k,2k+1}; both kv-halves stay on the same XCD
    int bid = blockIdx.x;
    int xcd = bid & 7, slot = bid >> 3;
    int bh = 2 * xcd + (slot & 1);
    int rem = slot >> 1;          // 0..63
    int qblk = rem >> 1;          // 0..31
    int kvh = rem & 1;
    int q0 = qblk * 128 + wv * 32;

    const short* kg = Kg + (size_t)bh * SLEN * HD;
    const short* vg = Vg + (size_t)bh * HD * SLEN;

    bf16x8 qf[4];
    {
        const short* qb = Q + ((size_t)bh * SLEN + q0 + q32) * HD + hi * 8;
        qf[0] = *(const bf16x8*)(qb);
        qf[1] = *(const bf16x8*)(qb + 16);
        qf[2] = *(const bf16x8*)(qb + 32);
        qf[3] = *(const bf16x8*)(qb + 48);
    }

    f32x16 oacc0 = {}, oacc1 = {};
    float mrun = 0.0f, bb = 0.0f, srun = 0.0f;

    int colsw = (((l & 7) ^ (l >> 3)) << 4);
    const char* kgB = (const char*)kg + (size_t)kvh * 32 * 8192;
    const char* vgB = (const char*)vg + (size_t)kvh * 32 * 128;
    int ksrc = (wv * 16 + (l >> 3)) * 128 + colsw;
    int vsrc = (wv * 16 + (l >> 3)) * 8192 + colsw;
    int wdst = wv * 2048;

#define STAGE(T, KB, VB) do { \
    gl2lds16(kgB + (size_t)(T) * 8192 + ksrc,          lds + (KB) * 8192 + wdst); \
    gl2lds16(kgB + (size_t)(T) * 8192 + ksrc + 1024,   lds + (KB) * 8192 + wdst + 1024); \
    gl2lds16(vgB + (size_t)(T) * 128 + vsrc,           lds + 16384 + (VB) * 8192 + wdst); \
    gl2lds16(vgB + (size_t)(T) * 128 + vsrc + 65536,   lds + 16384 + (VB) * 8192 + wdst + 1024); \
} while (0)

#define VMBAR() do { \
    asm volatile("s_waitcnt vmcnt(0) lgkmcnt(0)" ::: "memory"); \
    __builtin_amdgcn_s_barrier(); \
    asm volatile("" ::: "memory"); \
} while (0)

    int swz = (l & 7) << 4;
    int a0 = q32 * 128 + ((0 * 32 + hi * 16) ^ swz);
    int a1 = q32 * 128 + ((1 * 32 + hi * 16) ^ swz);
    int a2 = q32 * 128 + ((2 * 32 + hi * 16) ^ swz);
    int a3 = q32 * 128 + ((3 * 32 + hi * 16) ^ swz);

#define QKT(KB, D0, D1) do { \
    bb = mrun; \
    float nb_ = -mrun; \
    _Pragma("unroll") for (int r_ = 0; r_ < 16; ++r_) { D0[r_] = nb_; D1[r_] = nb_; } \
    __builtin_amdgcn_s_setprio(1); \
    { \
        bf16x8 k0_, k1_; \
        k0_ = *(const bf16x8*)(lds + a0 + (KB) * 8192); \
        k1_ = *(const bf16x8*)(lds + a0 + (KB) * 8192 + 4096); \
        D0 = __builtin_amdgcn_mfma_f32_32x32x16_bf16(k0_, qf[0], D0, 0, 0, 0); \
        D1 = __builtin_amdgcn_mfma_f32_32x32x16_bf16(k1_, qf[0], D1, 0, 0, 0); \
        k0_ = *(const bf16x8*)(lds + a1 + (KB) * 8192); \
        k1_ = *(const bf16x8*)(lds + a1 + (KB) * 8192 + 4096); \
        D0 = __builtin_amdgcn_mfma_f32_32x32x16_bf16(k0_, qf[1], D0, 0, 0, 0); \
        D1 = __builtin_amdgcn_mfma_f32_32x32x16_bf16(k1_, qf[1], D1, 0, 0, 0); \
        k0_ = *(const bf16x8*)(lds + a2 + (KB) * 8192); \
        k1_ = *(const bf16x8*)(lds + a2 + (KB) * 8192 + 4096); \
        D0 = __builtin_amdgcn_mfma_f32_32x32x16_bf16(k0_, qf[2], D0, 0, 0, 0); \
        D1 = __builtin_amdgcn_mfma_f32_32x32x16_bf16(k1_, qf[2], D1, 0, 0, 0); \
        k0_ = *(const bf16x8*)(lds + a3 + (KB) * 8192); \
        k1_ = *(const bf16x8*)(lds + a3 + (KB) * 8192 + 4096); \
        D0 = __builtin_amdgcn_mfma_f32_32x32x16_bf16(k0_, qf[3], D0, 0, 0, 0); \
        D1 = __builtin_amdgcn_mfma_f32_32x32x16_bf16(k1_, qf[3], D1, 0, 0, 0); \
    } \
    __builtin_amdgcn_s_setprio(0); \
} while (0)

#define PVKC(AK, SV, BASE, VB) do { \
    unsigned A0_ = cvt_pk(SV[(BASE) + 0], SV[(BASE) + 1]); \
    unsigned A1_ = cvt_pk(SV[(BASE) + 2], SV[(BASE) + 3]); \
    unsigned A2_ = cvt_pk(SV[(BASE) + 4], SV[(BASE) + 5]); \
    unsigned A3_ = cvt_pk(SV[(BASE) + 6], SV[(BASE) + 7]); \
    asm volatile("v_permlane32_swap_b32 %0, %1" : "+v"(A0_), "+v"(A2_)); \
    asm volatile("v_permlane32_swap_b32 %0, %1" : "+v"(A1_), "+v"(A3_)); \
    union { bf16x8 v; unsigned u[4]; } pf_; \
    pf_.u[0] = A0_; pf_.u[1] = A1_; pf_.u[2] = A2_; pf_.u[3] = A3_; \
    bf16x8 v0_ = *(const bf16x8*)(lds + (AK) + 16384 + (VB) * 8192); \
    bf16x8 v1_ = *(const bf16x8*)(lds + (AK) + 16384 + (VB) * 8192 + 4096); \
    oacc0 = __builtin_amdgcn_mfma_f32_32x32x16_bf16(v0_, pf_.v, oacc0, 0, 0, 0); \
    oacc1 = __builtin_amdgcn_mfma_f32_32x32x16_bf16(v1_, pf_.v, oacc1, 0, 0, 0); \
} while (0)

#define SMPV(VB, S0, S1) do { \
    float pa_ = S0[0], pb_ = S0[8], pc_ = S1[0], pd_ = S1[8]; \
    _Pragma("unroll") for (int r_ = 1; r_ < 8; ++r_) { \
        pa_ = fmaxf(pa_, S0[r_]); pb_ = fmaxf(pb_, S0[8 + r_]); \
        pc_ = fmaxf(pc_, S1[r_]); pd_ = fmaxf(pd_, S1[8 + r_]); \
    } \
    float pms_ = fmaxf(fmaxf(pa_, pb_), fmaxf(pc_, pd_)); \
    float c1_ = pms_, c2_ = pms_; \
    asm volatile("" : "+v"(c2_)); /* force distinct register */ \
    asm volatile("v_permlane32_swap_b32 %0, %1" : "+v"(c1_), "+v"(c2_)); \
    pms_ = fmaxf(c1_, c2_); \
    float db_ = mrun - bb; \
    if (!__all(pms_ <= db_ + 10.0f)) { \
        float mn_ = fmaxf(mrun, pms_ + bb); \
        float al_ = __builtin_amdgcn_exp2f(mrun - mn_); \
        _Pragma("unroll") for (int r_ = 0; r_ < 16; ++r_) { oacc0[r_] *= al_; oacc1[r_] *= al_; } \
        srun *= al_; \
        mrun = mn_; db_ = mn_ - bb; \
    } \
    if (__all(db_ == 0.0f)) { \
        _Pragma("unroll") for (int r_ = 0; r_ < 16; ++r_) { \
            S0[r_] = __builtin_amdgcn_exp2f(S0[r_]); \
            S1[r_] = __builtin_amdgcn_exp2f(S1[r_]); \
        } \
    } else { \
        _Pragma("unroll") for (int r_ = 0; r_ < 16; ++r_) { \
            S0[r_] = __builtin_amdgcn_exp2f(S0[r_] - db_); \
            S1[r_] = __builtin_amdgcn_exp2f(S1[r_] - db_); \
        } \
    } \
    { \
        float t0_ = 0.f, t1_ = 0.f, t2_ = 0.f, t3_ = 0.f; \
        _Pragma("unroll") for (int r_ = 0; r_ < 8; ++r_) { \
            t0_ += S0[r_]; t1_ += S0[8 + r_]; t2_ += S1[r_]; t3_ += S1[8 + r_]; \
        } \
        srun += (t0_ + t1_) + (t2_ + t3_); \
    } \
    __builtin_amdgcn_s_setprio(1); \
    PVKC(a0, S0, 0, VB); \
    PVKC(a1, S0, 8, VB); \
    PVKC(a2, S1, 0, VB); \
    PVKC(a3, S1, 8, VB); \
    __builtin_amdgcn_s_setprio(0); \
} while (0)

    f32x16 s0v, s1v;

    // prologue: stage tile 0 into bufs 0; drain
    STAGE(0, 0, 0);
    VMBAR();

    // steady state: stage ONE ahead; sequential QKT->SMPV per tile; 2-unrolled
    for (int m = 0; m < 15; ++m) {
        STAGE(2 * m + 1, 1, 1); QKT(0, s0v, s1v); SMPV(0, s0v, s1v); VMBAR();
        STAGE(2 * m + 2, 0, 0); QKT(1, s0v, s1v); SMPV(1, s0v, s1v); VMBAR();
    }
    // t=30: stage 31; t=31: no stage
    STAGE(31, 1, 1); QKT(0, s0v, s1v); SMPV(0, s0v, s1v); VMBAR();
    QKT(1, s0v, s1v); SMPV(1, s0v, s1v);

    // ---- epilogue: cross-half sum combine; store UNNORMALIZED fp32 partials ----
    float c1 = srun, c2 = srun;
    asm volatile("" : "+v"(c2));
    asm volatile("v_permlane32_swap_b32 %0, %1" : "+v"(c1), "+v"(c2));
    float ssum = c1 + c2;

    size_t p = ((size_t)(bh * 32 + qblk) * 2 + kvh);
    int ql = wv * 32 + q32;
    float* op = Opart + (p * 128 + ql) * 64;
#pragma unroll
    for (int g4 = 0; g4 < 4; ++g4) {
        float4 s0 = make_float4(oacc0[4 * g4 + 0], oacc0[4 * g4 + 1],
                                oacc0[4 * g4 + 2], oacc0[4 * g4 + 3]);
        float4 s1 = make_float4(oacc1[4 * g4 + 0], oacc1[4 * g4 + 1],
                                oacc1[4 * g4 + 2], oacc1[4 * g4 + 3]);
        *reinterpret_cast<float4*>(op + 8 * g4 + 4 * hi) = s0;
        *reinterpret_cast<float4*>(op + 32 + 8 * g4 + 4 * hi) = s1;
    }
    if (hi == 0) {
        float2 mlv; mlv.x = mrun; mlv.y = ssum;
        mlbuf[p * 128 + ql] = mlv;
    }
#undef STAGE
#undef VMBAR
#undef QKT
#undef PVKC
#undef SMPV
}

// ---------------- kernel M: merge the two kv-half partials -> aout bf16 ----------------
__launch_bounds__(256)
__global__ void k_merge(const float* __restrict__ Opart, const float2* __restrict__ mlbuf,
                        short* __restrict__ aout) {
    int bq = blockIdx.x;              // bh*32 + qblk
    int bh = bq >> 5, qblk = bq & 31;
    int tid = threadIdx.x;
    int dq = tid & 15;                // float4 index within 64-d row
    int qb = tid >> 4;                // 0..15
    size_t p1 = (size_t)bq * 2, p2 = p1 + 1;
    const float4* O1 = (const float4*)(Opart + p1 * 128 * 64);
    const float4* O2 = (const float4*)(Opart + p2 * 128 * 64);
    const float2* ml1 = mlbuf + p1 * 128;
    const float2* ml2 = mlbuf + p2 * 128;
    int b = bh >> 2, h = bh & 3;
    short* ob = aout + ((size_t)b * SLEN + qblk * 128) * CIN + h * HD;
#pragma unroll
    for (int j = 0; j < 8; ++j) {
        int ql = qb + 16 * j;
        float2 a = ml1[ql], c = ml2[ql];
        float mstar = fmaxf(a.x, c.x);
        float w1 = __builtin_amdgcn_exp2f(a.x - mstar);
        float w2 = __builtin_amdgcn_exp2f(c.x - mstar);
        float inv = 1.f / (a.y * w1 + c.y * w2);
        float4 o1 = O1[ql * 16 + dq];
        float4 o2 = O2[ql * 16 + dq];
        uint2 st;
        st.x = cvt_pk((o1.x * w1 + o2.x * w2) * inv, (o1.y * w1 + o2.y * w2) * inv);
        st.y = cvt_pk((o1.z * w1 + o2.z * w2) * inv, (o1.w * w1 + o2.w * w2) * inv);
        *reinterpret_cast<uint2*>(ob + (size_t)ql * CIN + dq * 4) = st;
    }
}

// ---------------- kernel C: proj GEMM + BN + SiLU -> fp32 out ----------------
__launch_bounds__(256)
__global__ void k_proj(const short* __restrict__ aout, const short* __restrict__ wbf,
                       const float* __restrict__ g, const float* __restrict__ be,
                       const float* __restrict__ mu, const float* __restrict__ va,
                       float* __restrict__ out) {
    int wv = threadIdx.x >> 6, l = threadIdx.x & 63, lr = l & 15, lg = l >> 4;
    int b = blockIdx.z;
    int s0 = blockIdx.x * 128 + wv * 32;
    int o0 = blockIdx.y * 64;
    f32x4 acc[2][4] = {};
    const short* aptr = aout + ((size_t)b * SLEN + s0 + lr) * CIN + lg * 8;
    const short* bptr = wbf + (size_t)(o0 + lr) * CIN + lg * 8;
#pragma unroll
    for (int k0 = 0; k0 < CIN; k0 += 32) {
        bf16x8 a0 = *(const bf16x8*)(aptr + k0);
        bf16x8 a1 = *(const bf16x8*)(aptr + 16 * CIN + k0);
#pragma unroll
        for (int oj = 0; oj < 4; oj++) {
            bf16x8 bb = *(const bf16x8*)(bptr + oj * 16 * CIN + k0);
            acc[0][oj] = __builtin_amdgcn_mfma_f32_16x16x32_bf16(a0, bb, acc[0][oj], 0, 0, 0);
            acc[1][oj] = __builtin_amdgcn_mfma_f32_16x16x32_bf16(a1, bb, acc[1][oj], 0, 0, 0);
        }
    }
#pragma unroll
    for (int oj = 0; oj < 4; oj++) {
        int o = o0 + oj * 16 + lr;
        float sc = g[o] * rsqrtf(va[o] + 1e-5f);
        float sh = be[o] - mu[o] * sc;
#pragma unroll
        for (int qi = 0; qi < 2; qi++) {
            float4 st;
            float* stp = &st.x;
#pragma unroll
            for (int i = 0; i < 4; i++) {
                float y = acc[qi][oj][i] * sc + sh;
                stp[i] = y / (1.f + __expf(-y));
            }
            int s = s0 + qi * 16 + lg * 4;
            *reinterpret_cast<float4*>(out + ((size_t)b * CIN + o) * SLEN + s) = st;
        }
    }
}

extern "C" void kernel_launch(void* const* d_in, const int* in_sizes, int n_in,
                              void* d_out, int out_size, void* d_ws, size_t ws_size,
                              hipStream_t stream) {
    const float* x    = (const float*)d_in[0];
    const float* qkvw = (const float*)d_in[1];
    const float* qg   = (const float*)d_in[2];
    const float* qbe  = (const float*)d_in[3];
    const float* qmu  = (const float*)d_in[4];
    const float* qva  = (const float*)d_in[5];
    const float* pw   = (const float*)d_in[6];
    const float* pg   = (const float*)d_in[7];
    const float* pbe  = (const float*)d_in[8];
    const float* pmu  = (const float*)d_in[9];
    const float* pva  = (const float*)d_in[10];
    float* out = (float*)d_out;

    char* ws = (char*)d_ws;
    short* qkvw_bf  = (short*)(ws);                 //    393,216 B
    short* projw_bf = (short*)(ws + 393216);        //    131,072 B
    short* Qb       = (short*)(ws + 524288);        //  8,388,608 B
    short* Kb       = (short*)(ws + 8912896);       //  8,388,608 B
    short* Vt       = (short*)(ws + 17301504);      //  8,388,608 B
    short* aout     = (short*)(ws + 25690112);      //  8,388,608 B
    float* Opart    = (float*)(ws + 34078720);      // 33,554,432 B
    float2* mlbuf   = (float2*)(ws + 67633152);     //  1,048,576 B

    k_convert_w<<<768, 256, 0, stream>>>(qkvw, pw, qkvw_bf, projw_bf);
    k_qkv<<<dim3(32, 12, 4), 256, 0, stream>>>(x, qkvw_bf, qg, qbe, qmu, qva, Qb, Kb, Vt);
    k_attn<<<1024, 256, 0, stream>>>(Qb, Kb, Vt, Opart, mlbuf);
    k_merge<<<512, 256, 0, stream>>>(Opart, mlbuf, aout);
    k_proj<<<dim3(32, 4, 4), 256, 0, stream>>>(aout, projw_bf, pg, pbe, pmu, pva, out);
}

// Round 13
// 160.482 us; speedup vs baseline: 5.6421x; 1.0456x over previous
//
#include <hip/hip_runtime.h>
#include <hip/hip_bf16.h>
#include <math.h>

#define SLEN 4096
#define CIN 256
#define C3 768
#define NH 4
#define HD 64
#define BATCH 4

typedef __attribute__((ext_vector_type(8))) short bf16x8;
typedef __attribute__((ext_vector_type(4))) float f32x4;
typedef __attribute__((ext_vector_type(16))) float f32x16;

typedef const __attribute__((address_space(1))) void GVoid;
typedef __attribute__((address_space(3))) void LVoid;

__device__ __forceinline__ void gl2lds16(const void* g, void* l) {
    __builtin_amdgcn_global_load_lds((GVoid*)g, (LVoid*)l, 16, 0, 0);
}

__device__ __forceinline__ short f2bf(float f) {
    union { float f; unsigned u; } v; v.f = f;
    unsigned r = v.u + 0x7fff + ((v.u >> 16) & 1);
    return (short)(r >> 16);
}

// single-instruction packed f32->bf16 (RNE) — no builtin on gfx950, inline asm per T12
__device__ __forceinline__ unsigned cvt_pk(float lo, float hi) {
    unsigned r;
    asm("v_cvt_pk_bf16_f32 %0, %1, %2" : "=v"(r) : "v"(lo), "v"(hi));
    return r;
}

// ---------------- kernel W: convert weights to bf16 ----------------
__global__ void k_convert_w(const float* __restrict__ qkvw, const float* __restrict__ projw,
                            short* __restrict__ qkvw_bf, short* __restrict__ projw_bf) {
    int i = blockIdx.x * 256 + threadIdx.x;
    if (i < C3 * CIN) qkvw_bf[i] = f2bf(qkvw[i]);
    if (i < CIN * CIN) projw_bf[i] = f2bf(projw[i]);
}

// ---------------- kernel A: fused transpose + QKV GEMM + BN + SiLU ----------------
// Reads x [b][c][s] fp32 directly (coalesced float4), stages 32k x 128s chunks as f32
// in LDS once per block, computes 192 outputs/block (12 oj) to cut the per-o-block
// x re-read from 12x to 4x (x is L3-resident; L3 BW was the k_qkv bottleneck).
// Q,K: [bh][s][d]; Vt: [bh][d][s]. Q pre-scaled by hd^-0.5 * log2(e).
__launch_bounds__(256)
__global__ void k_qkv(const float* __restrict__ x, const short* __restrict__ wbf,
                      const float* __restrict__ g, const float* __restrict__ be,
                      const float* __restrict__ mu, const float* __restrict__ va,
                      short* __restrict__ Q, short* __restrict__ Kb, short* __restrict__ Vt) {
    __shared__ __align__(16) float xt[32][136];   // [k-chunk][s], pad 136 keeps 16B rows
    int wv = threadIdx.x >> 6, l = threadIdx.x & 63, lr = l & 15, lg = l >> 4;
    int b = blockIdx.z;
    int sblk = blockIdx.x * 128;
    int s0 = sblk + wv * 32;
    int o0 = blockIdx.y * 192;

    // staging geometry: thread covers row c = tid>>3, 4 float4 segments
    int tc = threadIdx.x >> 3;
    int tg = threadIdx.x & 7;
    const float* xsrc = x + ((size_t)b * CIN + tc) * SLEN + sblk + tg * 4;

    f32x4 acc[2][12] = {};
    const short* bptr = wbf + (size_t)(o0 + lr) * CIN + lg * 8;
    const float* xrd0 = &xt[lg * 8][wv * 32 + 0 * 16 + lr];
    const float* xrd1 = &xt[lg * 8][wv * 32 + 1 * 16 + lr];

#pragma unroll
    for (int ch = 0; ch < 8; ++ch) {
        int k0 = ch * 32;
        __syncthreads();
        // stage chunk: x[b][k0 + tc][sblk .. sblk+127] -> xt[tc][s]
        const float* xs = xsrc + (size_t)k0 * SLEN;
#pragma unroll
        for (int j = 0; j < 4; ++j) {
            float4 v = *reinterpret_cast<const float4*>(xs + j * 32);
            *reinterpret_cast<float4*>(&xt[tc][tg * 4 + j * 32]) = v;
        }
        __syncthreads();

        // A-fragments: transposed reads + cvt_pk
        union { bf16x8 v; unsigned u[4]; } a0, a1;
#pragma unroll
        for (int p = 0; p < 4; ++p) {
            a0.u[p] = cvt_pk(xrd0[(2 * p) * 136], xrd0[(2 * p + 1) * 136]);
            a1.u[p] = cvt_pk(xrd1[(2 * p) * 136], xrd1[(2 * p + 1) * 136]);
        }
#pragma unroll
        for (int oj = 0; oj < 12; oj++) {
            bf16x8 bb = *(const bf16x8*)(bptr + oj * 16 * CIN + k0);
            acc[0][oj] = __builtin_amdgcn_mfma_f32_16x16x32_bf16(a0.v, bb, acc[0][oj], 0, 0, 0);
            acc[1][oj] = __builtin_amdgcn_mfma_f32_16x16x32_bf16(a1.v, bb, acc[1][oj], 0, 0, 0);
        }
    }

    const float QSC = 0.125f * 1.44269504088896f;
#pragma unroll
    for (int oj = 0; oj < 12; oj++) {
        int ob = o0 + oj * 16;          // 16-aligned: which/h/bh uniform per oj
        int which = ob >> 8;
        int h = (ob & 255) >> 6;
        int bh = b * NH + h;
        int o = ob + lr;
        float sc = g[o] * rsqrtf(va[o] + 1e-5f);
        float sh = be[o] - mu[o] * sc;
        int d = o & 63;
#pragma unroll
        for (int qi = 0; qi < 2; qi++) {
#pragma unroll
            for (int i = 0; i < 4; i++) {
                float y = acc[qi][oj][i] * sc + sh;
                float z = y / (1.f + __expf(-y));
                int s = s0 + qi * 16 + lg * 4 + i;
                if (which == 0) {
                    Q[((size_t)bh * SLEN + s) * HD + d] = f2bf(z * QSC);
                } else if (which == 1) {
                    Kb[((size_t)bh * SLEN + s) * HD + d] = f2bf(z);
                } else {
                    Vt[((size_t)bh * HD + d) * SLEN + s] = f2bf(z);
                }
            }
        }
    }
}

// ---------------- kernel ATTN: flash attention, pipelined swapped-QK^T ----
// (round-6/9 structure, best measured: 95.2 us)
// 4 waves/block, 32 q-rows/wave, KVBLK=64. K 2-buf @ lds+0, V 4-buf @ lds+16384.
// Staging via global_load_lds width=16: linear LDS dest + PRE-SWIZZLED per-lane global
// source. One vmcnt(0)+barrier per tile. XCD-aware decode: XCD k owns bh {2k,2k+1}.
// S^T = mfma_32x32x16(K, Q): lane holds 32 P values for q = lane&31.
__launch_bounds__(256, 2)
__global__ void k_attn(const short* __restrict__ Q, const short* __restrict__ Kg,
                       const short* __restrict__ Vg, short* __restrict__ aout) {
    __shared__ __align__(16) char lds[16384 + 32768];
    int tid = threadIdx.x;
    int wv = tid >> 6, l = tid & 63;
    int q32 = l & 31;
    int hi  = l >> 5;

    int bid = blockIdx.x;
    int xcd = bid & 7, slot = bid >> 3;
    int bh = 2 * xcd + (slot & 1);
    int q0 = (slot >> 1) * 128 + wv * 32;

    const short* kg = Kg + (size_t)bh * SLEN * HD;
    const short* vg = Vg + (size_t)bh * HD * SLEN;

    bf16x8 qf[4];
    {
        const short* qb = Q + ((size_t)bh * SLEN + q0 + q32) * HD + hi * 8;
        qf[0] = *(const bf16x8*)(qb);
        qf[1] = *(const bf16x8*)(qb + 16);
        qf[2] = *(const bf16x8*)(qb + 32);
        qf[3] = *(const bf16x8*)(qb + 48);
    }

    bf16x8 ones;
#pragma unroll
    for (int e = 0; e < 8; ++e) ones[e] = (short)0x3F80;

    f32x16 oacc0 = {}, oacc1 = {}, sacc = {};
    float mrun = 0.0f, bA = 0.0f, bB = 0.0f;

    int colsw = (((l & 7) ^ (l >> 3)) << 4);
    const char* kgB = (const char*)kg;
    const char* vgB = (const char*)vg;
    int ksrc = (wv * 16 + (l >> 3)) * 128 + colsw;
    int vsrc = (wv * 16 + (l >> 3)) * 8192 + colsw;
    int wdst = wv * 2048;

#define STAGE(T, KB, VB) do { \
    gl2lds16(kgB + (size_t)(T) * 8192 + ksrc,          lds + (KB) * 8192 + wdst); \
    gl2lds16(kgB + (size_t)(T) * 8192 + ksrc + 1024,   lds + (KB) * 8192 + wdst + 1024); \
    gl2lds16(vgB + (size_t)(T) * 128 + vsrc,           lds + 16384 + (VB) * 8192 + wdst); \
    gl2lds16(vgB + (size_t)(T) * 128 + vsrc + 65536,   lds + 16384 + (VB) * 8192 + wdst + 1024); \
} while (0)

#define VMBAR() do { \
    asm volatile("s_waitcnt vmcnt(0) lgkmcnt(0)" ::: "memory"); \
    __builtin_amdgcn_s_barrier(); \
    asm volatile("" ::: "memory"); \
} while (0)

    int swz = (l & 7) << 4;
    int a0 = q32 * 128 + ((0 * 32 + hi * 16) ^ swz);
    int a1 = q32 * 128 + ((1 * 32 + hi * 16) ^ swz);
    int a2 = q32 * 128 + ((2 * 32 + hi * 16) ^ swz);
    int a3 = q32 * 128 + ((3 * 32 + hi * 16) ^ swz);

#define QKT(KB, D0, D1, BSET) do { \
    BSET = mrun; \
    float nb_ = -mrun; \
    _Pragma("unroll") for (int r_ = 0; r_ < 16; ++r_) { D0[r_] = nb_; D1[r_] = nb_; } \
    __builtin_amdgcn_s_setprio(1); \
    { \
        bf16x8 k0_, k1_; \
        k0_ = *(const bf16x8*)(lds + a0 + (KB) * 8192); \
        k1_ = *(const bf16x8*)(lds + a0 + (KB) * 8192 + 4096); \
        D0 = __builtin_amdgcn_mfma_f32_32x32x16_bf16(k0_, qf[0], D0, 0, 0, 0); \
        D1 = __builtin_amdgcn_mfma_f32_32x32x16_bf16(k1_, qf[0], D1, 0, 0, 0); \
        k0_ = *(const bf16x8*)(lds + a1 + (KB) * 8192); \
        k1_ = *(const bf16x8*)(lds + a1 + (KB) * 8192 + 4096); \
        D0 = __builtin_amdgcn_mfma_f32_32x32x16_bf16(k0_, qf[1], D0, 0, 0, 0); \
        D1 = __builtin_amdgcn_mfma_f32_32x32x16_bf16(k1_, qf[1], D1, 0, 0, 0); \
        k0_ = *(const bf16x8*)(lds + a2 + (KB) * 8192); \
        k1_ = *(const bf16x8*)(lds + a2 + (KB) * 8192 + 4096); \
        D0 = __builtin_amdgcn_mfma_f32_32x32x16_bf16(k0_, qf[2], D0, 0, 0, 0); \
        D1 = __builtin_amdgcn_mfma_f32_32x32x16_bf16(k1_, qf[2], D1, 0, 0, 0); \
        k0_ = *(const bf16x8*)(lds + a3 + (KB) * 8192); \
        k1_ = *(const bf16x8*)(lds + a3 + (KB) * 8192 + 4096); \
        D0 = __builtin_amdgcn_mfma_f32_32x32x16_bf16(k0_, qf[3], D0, 0, 0, 0); \
        D1 = __builtin_amdgcn_mfma_f32_32x32x16_bf16(k1_, qf[3], D1, 0, 0, 0); \
    } \
    __builtin_amdgcn_s_setprio(0); \
} while (0)

#define PVKC(AK, SV, BASE, VB) do { \
    unsigned A0_ = cvt_pk(SV[(BASE) + 0], SV[(BASE) + 1]); \
    unsigned A1_ = cvt_pk(SV[(BASE) + 2], SV[(BASE) + 3]); \
    unsigned A2_ = cvt_pk(SV[(BASE) + 4], SV[(BASE) + 5]); \
    unsigned A3_ = cvt_pk(SV[(BASE) + 6], SV[(BASE) + 7]); \
    asm volatile("v_permlane32_swap_b32 %0, %1" : "+v"(A0_), "+v"(A2_)); \
    asm volatile("v_permlane32_swap_b32 %0, %1" : "+v"(A1_), "+v"(A3_)); \
    union { bf16x8 v; unsigned u[4]; } pf_; \
    pf_.u[0] = A0_; pf_.u[1] = A1_; pf_.u[2] = A2_; pf_.u[3] = A3_; \
    bf16x8 v0_ = *(const bf16x8*)(lds + (AK) + 16384 + (VB) * 8192); \
    bf16x8 v1_ = *(const bf16x8*)(lds + (AK) + 16384 + (VB) * 8192 + 4096); \
    oacc0 = __builtin_amdgcn_mfma_f32_32x32x16_bf16(v0_, pf_.v, oacc0, 0, 0, 0); \
    oacc1 = __builtin_amdgcn_mfma_f32_32x32x16_bf16(v1_, pf_.v, oacc1, 0, 0, 0); \
    sacc  = __builtin_amdgcn_mfma_f32_32x32x16_bf16(ones, pf_.v, sacc, 0, 0, 0); \
} while (0)

#define SMPV(VB, S0, S1, BSET) do { \
    float pa_ = S0[0], pb_ = S0[8], pc_ = S1[0], pd_ = S1[8]; \
    _Pragma("unroll") for (int r_ = 1; r_ < 8; ++r_) { \
        pa_ = fmaxf(pa_, S0[r_]); pb_ = fmaxf(pb_, S0[8 + r_]); \
        pc_ = fmaxf(pc_, S1[r_]); pd_ = fmaxf(pd_, S1[8 + r_]); \
    } \
    float pms_ = fmaxf(fmaxf(pa_, pb_), fmaxf(pc_, pd_)); \
    float c1_ = pms_, c2_ = pms_; \
    asm volatile("" : "+v"(c2_)); /* force distinct register */ \
    asm volatile("v_permlane32_swap_b32 %0, %1" : "+v"(c1_), "+v"(c2_)); \
    pms_ = fmaxf(c1_, c2_); \
    float db_ = mrun - (BSET); \
    if (!__all(pms_ <= db_ + 10.0f)) { \
        float mn_ = fmaxf(mrun, pms_ + (BSET)); \
        float al_ = __builtin_amdgcn_exp2f(mrun - mn_); \
        _Pragma("unroll") for (int r_ = 0; r_ < 16; ++r_) { oacc0[r_] *= al_; oacc1[r_] *= al_; } \
        sacc[0] *= al_; \
        mrun = mn_; db_ = mn_ - (BSET); \
    } \
    if (__all(db_ == 0.0f)) { \
        _Pragma("unroll") for (int r_ = 0; r_ < 16; ++r_) { \
            S0[r_] = __builtin_amdgcn_exp2f(S0[r_]); \
            S1[r_] = __builtin_amdgcn_exp2f(S1[r_]); \
        } \
    } else { \
        _Pragma("unroll") for (int r_ = 0; r_ < 16; ++r_) { \
            S0[r_] = __builtin_amdgcn_exp2f(S0[r_] - db_); \
            S1[r_] = __builtin_amdgcn_exp2f(S1[r_] - db_); \
        } \
    } \
    __builtin_amdgcn_s_setprio(1); \
    PVKC(a0, S0, 0, VB); \
    PVKC(a1, S0, 8, VB); \
    PVKC(a2, S1, 0, VB); \
    PVKC(a3, S1, 8, VB); \
    __builtin_amdgcn_s_setprio(0); \
} while (0)

    f32x16 sA0, sA1, sB0, sB1;

    // prologue: stage 0; drain; stage 1 + QK(0); drain
    STAGE(0, 0, 0);
    VMBAR();
    STAGE(1, 1, 1);
    QKT(0, sA0, sA1, bA);
    VMBAR();

    // steady state: tiles 1..60, unroll 4 (all buffer indices literal)
    for (int j = 0; j < 15; ++j) {
        STAGE(4 * j + 2, 0, 2); QKT(1, sB0, sB1, bB); SMPV(0, sA0, sA1, bA); VMBAR();
        STAGE(4 * j + 3, 1, 3); QKT(0, sA0, sA1, bA); SMPV(1, sB0, sB1, bB); VMBAR();
        STAGE(4 * j + 4, 0, 0); QKT(1, sB0, sB1, bB); SMPV(2, sA0, sA1, bA); VMBAR();
        STAGE(4 * j + 5, 1, 1); QKT(0, sA0, sA1, bA); SMPV(3, sB0, sB1, bB); VMBAR();
    }
    // t = 61
    STAGE(62, 0, 2); QKT(1, sB0, sB1, bB); SMPV(0, sA0, sA1, bA); VMBAR();
    // t = 62
    STAGE(63, 1, 3); QKT(0, sA0, sA1, bA); SMPV(1, sB0, sB1, bB); VMBAR();
    // t = 63
    QKT(1, sB0, sB1, bB); SMPV(2, sA0, sA1, bA);
    SMPV(3, sB0, sB1, bB);

    // ---- epilogue: O^T/l -> aout [b][s][c] bf16 ----
    float inv = 1.f / sacc[0];
    int b = bh >> 2, h = bh & 3;
    short* ob = aout + ((size_t)b * SLEN + q0 + q32) * CIN + h * HD;
#pragma unroll
    for (int g4 = 0; g4 < 4; ++g4) {
        uint2 st0, st1;
        st0.x = cvt_pk(oacc0[4 * g4 + 0] * inv, oacc0[4 * g4 + 1] * inv);
        st0.y = cvt_pk(oacc0[4 * g4 + 2] * inv, oacc0[4 * g4 + 3] * inv);
        st1.x = cvt_pk(oacc1[4 * g4 + 0] * inv, oacc1[4 * g4 + 1] * inv);
        st1.y = cvt_pk(oacc1[4 * g4 + 2] * inv, oacc1[4 * g4 + 3] * inv);
        *(uint2*)(ob + 8 * g4 + 4 * hi) = st0;
        *(uint2*)(ob + 32 + 8 * g4 + 4 * hi) = st1;
    }
#undef STAGE
#undef VMBAR
#undef QKT
#undef PVKC
#undef SMPV
}

// ---------------- kernel C: proj GEMM + BN + SiLU -> fp32 out ----------------
__launch_bounds__(256)
__global__ void k_proj(const short* __restrict__ aout, const short* __restrict__ wbf,
                       const float* __restrict__ g, const float* __restrict__ be,
                       const float* __restrict__ mu, const float* __restrict__ va,
                       float* __restrict__ out) {
    int wv = threadIdx.x >> 6, l = threadIdx.x & 63, lr = l & 15, lg = l >> 4;
    int b = blockIdx.z;
    int s0 = blockIdx.x * 128 + wv * 32;
    int o0 = blockIdx.y * 64;
    f32x4 acc[2][4] = {};
    const short* aptr = aout + ((size_t)b * SLEN + s0 + lr) * CIN + lg * 8;
    const short* bptr = wbf + (size_t)(o0 + lr) * CIN + lg * 8;
#pragma unroll
    for (int k0 = 0; k0 < CIN; k0 += 32) {
        bf16x8 a0 = *(const bf16x8*)(aptr + k0);
        bf16x8 a1 = *(const bf16x8*)(aptr + 16 * CIN + k0);
#pragma unroll
        for (int oj = 0; oj < 4; oj++) {
            bf16x8 bb = *(const bf16x8*)(bptr + oj * 16 * CIN + k0);
            acc[0][oj] = __builtin_amdgcn_mfma_f32_16x16x32_bf16(a0, bb, acc[0][oj], 0, 0, 0);
            acc[1][oj] = __builtin_amdgcn_mfma_f32_16x16x32_bf16(a1, bb, acc[1][oj], 0, 0, 0);
        }
    }
#pragma unroll
    for (int oj = 0; oj < 4; oj++) {
        int o = o0 + oj * 16 + lr;
        float sc = g[o] * rsqrtf(va[o] + 1e-5f);
        float sh = be[o] - mu[o] * sc;
#pragma unroll
        for (int qi = 0; qi < 2; qi++) {
            float4 st;
            float* stp = &st.x;
#pragma unroll
            for (int i = 0; i < 4; i++) {
                float y = acc[qi][oj][i] * sc + sh;
                stp[i] = y / (1.f + __expf(-y));
            }
            int s = s0 + qi * 16 + lg * 4;
            *reinterpret_cast<float4*>(out + ((size_t)b * CIN + o) * SLEN + s) = st;
        }
    }
}

extern "C" void kernel_launch(void* const* d_in, const int* in_sizes, int n_in,
                              void* d_out, int out_size, void* d_ws, size_t ws_size,
                              hipStream_t stream) {
    const float* x    = (const float*)d_in[0];
    const float* qkvw = (const float*)d_in[1];
    const float* qg   = (const float*)d_in[2];
    const float* qbe  = (const float*)d_in[3];
    const float* qmu  = (const float*)d_in[4];
    const float* qva  = (const float*)d_in[5];
    const float* pw   = (const float*)d_in[6];
    const float* pg   = (const float*)d_in[7];
    const float* pbe  = (const float*)d_in[8];
    const float* pmu  = (const float*)d_in[9];
    const float* pva  = (const float*)d_in[10];
    float* out = (float*)d_out;

    char* ws = (char*)d_ws;
    short* qkvw_bf  = (short*)(ws);                 //    393,216 B
    short* projw_bf = (short*)(ws + 393216);        //    131,072 B
    short* Qb       = (short*)(ws + 524288);        //  8,388,608 B
    short* Kb       = (short*)(ws + 8912896);       //  8,388,608 B
    short* Vt       = (short*)(ws + 17301504);      //  8,388,608 B
    short* aout     = (short*)(ws + 25690112);      //  8,388,608 B

    k_convert_w<<<768, 256, 0, stream>>>(qkvw, pw, qkvw_bf, projw_bf);
    k_qkv<<<dim3(32, 4, 4), 256, 0, stream>>>(x, qkvw_bf, qg, qbe, qmu, qva, Qb, Kb, Vt);
    k_attn<<<512, 256, 0, stream>>>(Qb, Kb, Vt, aout);
    k_proj<<<dim3(32, 4, 4), 256, 0, stream>>>(aout, projw_bf, pg, pbe, pmu, pva, out);
}

// Round 14
// 156.227 us; speedup vs baseline: 5.7958x; 1.0272x over previous
//
#include <hip/hip_runtime.h>
#include <hip/hip_bf16.h>
#include <math.h>

#define SLEN 4096
#define CIN 256
#define C3 768
#define NH 4
#define HD 64
#define BATCH 4

typedef __attribute__((ext_vector_type(8))) short bf16x8;
typedef __attribute__((ext_vector_type(4))) float f32x4;
typedef __attribute__((ext_vector_type(16))) float f32x16;

typedef const __attribute__((address_space(1))) void GVoid;
typedef __attribute__((address_space(3))) void LVoid;

__device__ __forceinline__ void gl2lds16(const void* g, void* l) {
    __builtin_amdgcn_global_load_lds((GVoid*)g, (LVoid*)l, 16, 0, 0);
}

__device__ __forceinline__ short f2bf(float f) {
    union { float f; unsigned u; } v; v.f = f;
    unsigned r = v.u + 0x7fff + ((v.u >> 16) & 1);
    return (short)(r >> 16);
}

// single-instruction packed f32->bf16 (RNE) — no builtin on gfx950, inline asm per T12
__device__ __forceinline__ unsigned cvt_pk(float lo, float hi) {
    unsigned r;
    asm("v_cvt_pk_bf16_f32 %0, %1, %2" : "=v"(r) : "v"(lo), "v"(hi));
    return r;
}

// ---------------- kernel W: convert weights to bf16 ----------------
__global__ void k_convert_w(const float* __restrict__ qkvw, const float* __restrict__ projw,
                            short* __restrict__ qkvw_bf, short* __restrict__ projw_bf) {
    int i = blockIdx.x * 256 + threadIdx.x;
    if (i < C3 * CIN) qkvw_bf[i] = f2bf(qkvw[i]);
    if (i < CIN * CIN) projw_bf[i] = f2bf(projw[i]);
}

// ---------------- kernel A: fused transpose + QKV GEMM + BN + SiLU ----------------
// Reads x [b][c][s] fp32 directly (coalesced float4), stages 32k x 128s chunks as f32
// in LDS, computes 128 outputs/block (8 oj): acc[2][8]=64 AGPR + ~90 VGPR ~= 155
// combined -> 3 waves/SIMD (occupancy-neutral point; r12's 192-wide fell to 2/SIMD).
// x L3 re-read 12x -> 6x. Q,K: [bh][s][d]; Vt: [bh][d][s]. Q pre-scaled.
__launch_bounds__(256)
__global__ void k_qkv(const float* __restrict__ x, const short* __restrict__ wbf,
                      const float* __restrict__ g, const float* __restrict__ be,
                      const float* __restrict__ mu, const float* __restrict__ va,
                      short* __restrict__ Q, short* __restrict__ Kb, short* __restrict__ Vt) {
    __shared__ __align__(16) float xt[32][136];   // [k-chunk][s], pad 136 keeps 16B rows
    int wv = threadIdx.x >> 6, l = threadIdx.x & 63, lr = l & 15, lg = l >> 4;
    int b = blockIdx.z;
    int sblk = blockIdx.x * 128;
    int s0 = sblk + wv * 32;
    int o0 = blockIdx.y * 128;

    // staging geometry: thread covers row c = tid>>3, 4 float4 segments
    int tc = threadIdx.x >> 3;
    int tg = threadIdx.x & 7;
    const float* xsrc = x + ((size_t)b * CIN + tc) * SLEN + sblk + tg * 4;

    f32x4 acc[2][8] = {};
    const short* bptr = wbf + (size_t)(o0 + lr) * CIN + lg * 8;
    const float* xrd0 = &xt[lg * 8][wv * 32 + 0 * 16 + lr];
    const float* xrd1 = &xt[lg * 8][wv * 32 + 1 * 16 + lr];

#pragma unroll
    for (int ch = 0; ch < 8; ++ch) {
        int k0 = ch * 32;
        __syncthreads();
        // stage chunk: x[b][k0 + tc][sblk .. sblk+127] -> xt[tc][s]
        const float* xs = xsrc + (size_t)k0 * SLEN;
#pragma unroll
        for (int j = 0; j < 4; ++j) {
            float4 v = *reinterpret_cast<const float4*>(xs + j * 32);
            *reinterpret_cast<float4*>(&xt[tc][tg * 4 + j * 32]) = v;
        }
        __syncthreads();

        // A-fragments: transposed reads + cvt_pk
        union { bf16x8 v; unsigned u[4]; } a0, a1;
#pragma unroll
        for (int p = 0; p < 4; ++p) {
            a0.u[p] = cvt_pk(xrd0[(2 * p) * 136], xrd0[(2 * p + 1) * 136]);
            a1.u[p] = cvt_pk(xrd1[(2 * p) * 136], xrd1[(2 * p + 1) * 136]);
        }
#pragma unroll
        for (int oj = 0; oj < 8; oj++) {
            bf16x8 bb = *(const bf16x8*)(bptr + oj * 16 * CIN + k0);
            acc[0][oj] = __builtin_amdgcn_mfma_f32_16x16x32_bf16(a0.v, bb, acc[0][oj], 0, 0, 0);
            acc[1][oj] = __builtin_amdgcn_mfma_f32_16x16x32_bf16(a1.v, bb, acc[1][oj], 0, 0, 0);
        }
    }

    const float QSC = 0.125f * 1.44269504088896f;
#pragma unroll
    for (int oj = 0; oj < 8; oj++) {
        int ob = o0 + oj * 16;          // 16-aligned: which/h/bh uniform per oj
        int which = ob >> 8;
        int h = (ob & 255) >> 6;
        int bh = b * NH + h;
        int o = ob + lr;
        float sc = g[o] * rsqrtf(va[o] + 1e-5f);
        float sh = be[o] - mu[o] * sc;
        int d = o & 63;
#pragma unroll
        for (int qi = 0; qi < 2; qi++) {
#pragma unroll
            for (int i = 0; i < 4; i++) {
                float y = acc[qi][oj][i] * sc + sh;
                float z = y / (1.f + __expf(-y));
                int s = s0 + qi * 16 + lg * 4 + i;
                if (which == 0) {
                    Q[((size_t)bh * SLEN + s) * HD + d] = f2bf(z * QSC);
                } else if (which == 1) {
                    Kb[((size_t)bh * SLEN + s) * HD + d] = f2bf(z);
                } else {
                    Vt[((size_t)bh * HD + d) * SLEN + s] = f2bf(z);
                }
            }
        }
    }
}

// ---------------- kernel ATTN: flash attention, pipelined swapped-QK^T ----
// (round-6/9 structure, best measured: 95.2 us — register-equilibrium design)
// 4 waves/block, 32 q-rows/wave, KVBLK=64. K 2-buf @ lds+0, V 4-buf @ lds+16384.
// Staging via global_load_lds width=16: linear LDS dest + PRE-SWIZZLED per-lane global
// source. One vmcnt(0)+barrier per tile. XCD-aware decode: XCD k owns bh {2k,2k+1}.
// S^T = mfma_32x32x16(K, Q): lane holds 32 P values for q = lane&31.
__launch_bounds__(256, 2)
__global__ void k_attn(const short* __restrict__ Q, const short* __restrict__ Kg,
                       const short* __restrict__ Vg, short* __restrict__ aout) {
    __shared__ __align__(16) char lds[16384 + 32768];
    int tid = threadIdx.x;
    int wv = tid >> 6, l = tid & 63;
    int q32 = l & 31;
    int hi  = l >> 5;

    int bid = blockIdx.x;
    int xcd = bid & 7, slot = bid >> 3;
    int bh = 2 * xcd + (slot & 1);
    int q0 = (slot >> 1) * 128 + wv * 32;

    const short* kg = Kg + (size_t)bh * SLEN * HD;
    const short* vg = Vg + (size_t)bh * HD * SLEN;

    bf16x8 qf[4];
    {
        const short* qb = Q + ((size_t)bh * SLEN + q0 + q32) * HD + hi * 8;
        qf[0] = *(const bf16x8*)(qb);
        qf[1] = *(const bf16x8*)(qb + 16);
        qf[2] = *(const bf16x8*)(qb + 32);
        qf[3] = *(const bf16x8*)(qb + 48);
    }

    bf16x8 ones;
#pragma unroll
    for (int e = 0; e < 8; ++e) ones[e] = (short)0x3F80;

    f32x16 oacc0 = {}, oacc1 = {}, sacc = {};
    float mrun = 0.0f, bA = 0.0f, bB = 0.0f;

    int colsw = (((l & 7) ^ (l >> 3)) << 4);
    const char* kgB = (const char*)kg;
    const char* vgB = (const char*)vg;
    int ksrc = (wv * 16 + (l >> 3)) * 128 + colsw;
    int vsrc = (wv * 16 + (l >> 3)) * 8192 + colsw;
    int wdst = wv * 2048;

#define STAGE(T, KB, VB) do { \
    gl2lds16(kgB + (size_t)(T) * 8192 + ksrc,          lds + (KB) * 8192 + wdst); \
    gl2lds16(kgB + (size_t)(T) * 8192 + ksrc + 1024,   lds + (KB) * 8192 + wdst + 1024); \
    gl2lds16(vgB + (size_t)(T) * 128 + vsrc,           lds + 16384 + (VB) * 8192 + wdst); \
    gl2lds16(vgB + (size_t)(T) * 128 + vsrc + 65536,   lds + 16384 + (VB) * 8192 + wdst + 1024); \
} while (0)

#define VMBAR() do { \
    asm volatile("s_waitcnt vmcnt(0) lgkmcnt(0)" ::: "memory"); \
    __builtin_amdgcn_s_barrier(); \
    asm volatile("" ::: "memory"); \
} while (0)

    int swz = (l & 7) << 4;
    int a0 = q32 * 128 + ((0 * 32 + hi * 16) ^ swz);
    int a1 = q32 * 128 + ((1 * 32 + hi * 16) ^ swz);
    int a2 = q32 * 128 + ((2 * 32 + hi * 16) ^ swz);
    int a3 = q32 * 128 + ((3 * 32 + hi * 16) ^ swz);

#define QKT(KB, D0, D1, BSET) do { \
    BSET = mrun; \
    float nb_ = -mrun; \
    _Pragma("unroll") for (int r_ = 0; r_ < 16; ++r_) { D0[r_] = nb_; D1[r_] = nb_; } \
    __builtin_amdgcn_s_setprio(1); \
    { \
        bf16x8 k0_, k1_; \
        k0_ = *(const bf16x8*)(lds + a0 + (KB) * 8192); \
        k1_ = *(const bf16x8*)(lds + a0 + (KB) * 8192 + 4096); \
        D0 = __builtin_amdgcn_mfma_f32_32x32x16_bf16(k0_, qf[0], D0, 0, 0, 0); \
        D1 = __builtin_amdgcn_mfma_f32_32x32x16_bf16(k1_, qf[0], D1, 0, 0, 0); \
        k0_ = *(const bf16x8*)(lds + a1 + (KB) * 8192); \
        k1_ = *(const bf16x8*)(lds + a1 + (KB) * 8192 + 4096); \
        D0 = __builtin_amdgcn_mfma_f32_32x32x16_bf16(k0_, qf[1], D0, 0, 0, 0); \
        D1 = __builtin_amdgcn_mfma_f32_32x32x16_bf16(k1_, qf[1], D1, 0, 0, 0); \
        k0_ = *(const bf16x8*)(lds + a2 + (KB) * 8192); \
        k1_ = *(const bf16x8*)(lds + a2 + (KB) * 8192 + 4096); \
        D0 = __builtin_amdgcn_mfma_f32_32x32x16_bf16(k0_, qf[2], D0, 0, 0, 0); \
        D1 = __builtin_amdgcn_mfma_f32_32x32x16_bf16(k1_, qf[2], D1, 0, 0, 0); \
        k0_ = *(const bf16x8*)(lds + a3 + (KB) * 8192); \
        k1_ = *(const bf16x8*)(lds + a3 + (KB) * 8192 + 4096); \
        D0 = __builtin_amdgcn_mfma_f32_32x32x16_bf16(k0_, qf[3], D0, 0, 0, 0); \
        D1 = __builtin_amdgcn_mfma_f32_32x32x16_bf16(k1_, qf[3], D1, 0, 0, 0); \
    } \
    __builtin_amdgcn_s_setprio(0); \
} while (0)

#define PVKC(AK, SV, BASE, VB) do { \
    unsigned A0_ = cvt_pk(SV[(BASE) + 0], SV[(BASE) + 1]); \
    unsigned A1_ = cvt_pk(SV[(BASE) + 2], SV[(BASE) + 3]); \
    unsigned A2_ = cvt_pk(SV[(BASE) + 4], SV[(BASE) + 5]); \
    unsigned A3_ = cvt_pk(SV[(BASE) + 6], SV[(BASE) + 7]); \
    asm volatile("v_permlane32_swap_b32 %0, %1" : "+v"(A0_), "+v"(A2_)); \
    asm volatile("v_permlane32_swap_b32 %0, %1" : "+v"(A1_), "+v"(A3_)); \
    union { bf16x8 v; unsigned u[4]; } pf_; \
    pf_.u[0] = A0_; pf_.u[1] = A1_; pf_.u[2] = A2_; pf_.u[3] = A3_; \
    bf16x8 v0_ = *(const bf16x8*)(lds + (AK) + 16384 + (VB) * 8192); \
    bf16x8 v1_ = *(const bf16x8*)(lds + (AK) + 16384 + (VB) * 8192 + 4096); \
    oacc0 = __builtin_amdgcn_mfma_f32_32x32x16_bf16(v0_, pf_.v, oacc0, 0, 0, 0); \
    oacc1 = __builtin_amdgcn_mfma_f32_32x32x16_bf16(v1_, pf_.v, oacc1, 0, 0, 0); \
    sacc  = __builtin_amdgcn_mfma_f32_32x32x16_bf16(ones, pf_.v, sacc, 0, 0, 0); \
} while (0)

#define SMPV(VB, S0, S1, BSET) do { \
    float pa_ = S0[0], pb_ = S0[8], pc_ = S1[0], pd_ = S1[8]; \
    _Pragma("unroll") for (int r_ = 1; r_ < 8; ++r_) { \
        pa_ = fmaxf(pa_, S0[r_]); pb_ = fmaxf(pb_, S0[8 + r_]); \
        pc_ = fmaxf(pc_, S1[r_]); pd_ = fmaxf(pd_, S1[8 + r_]); \
    } \
    float pms_ = fmaxf(fmaxf(pa_, pb_), fmaxf(pc_, pd_)); \
    float c1_ = pms_, c2_ = pms_; \
    asm volatile("" : "+v"(c2_)); /* force distinct register */ \
    asm volatile("v_permlane32_swap_b32 %0, %1" : "+v"(c1_), "+v"(c2_)); \
    pms_ = fmaxf(c1_, c2_); \
    float db_ = mrun - (BSET); \
    if (!__all(pms_ <= db_ + 10.0f)) { \
        float mn_ = fmaxf(mrun, pms_ + (BSET)); \
        float al_ = __builtin_amdgcn_exp2f(mrun - mn_); \
        _Pragma("unroll") for (int r_ = 0; r_ < 16; ++r_) { oacc0[r_] *= al_; oacc1[r_] *= al_; } \
        sacc[0] *= al_; \
        mrun = mn_; db_ = mn_ - (BSET); \
    } \
    if (__all(db_ == 0.0f)) { \
        _Pragma("unroll") for (int r_ = 0; r_ < 16; ++r_) { \
            S0[r_] = __builtin_amdgcn_exp2f(S0[r_]); \
            S1[r_] = __builtin_amdgcn_exp2f(S1[r_]); \
        } \
    } else { \
        _Pragma("unroll") for (int r_ = 0; r_ < 16; ++r_) { \
            S0[r_] = __builtin_amdgcn_exp2f(S0[r_] - db_); \
            S1[r_] = __builtin_amdgcn_exp2f(S1[r_] - db_); \
        } \
    } \
    __builtin_amdgcn_s_setprio(1); \
    PVKC(a0, S0, 0, VB); \
    PVKC(a1, S0, 8, VB); \
    PVKC(a2, S1, 0, VB); \
    PVKC(a3, S1, 8, VB); \
    __builtin_amdgcn_s_setprio(0); \
} while (0)

    f32x16 sA0, sA1, sB0, sB1;

    // prologue: stage 0; drain; stage 1 + QK(0); drain
    STAGE(0, 0, 0);
    VMBAR();
    STAGE(1, 1, 1);
    QKT(0, sA0, sA1, bA);
    VMBAR();

    // steady state: tiles 1..60, unroll 4 (all buffer indices literal)
    for (int j = 0; j < 15; ++j) {
        STAGE(4 * j + 2, 0, 2); QKT(1, sB0, sB1, bB); SMPV(0, sA0, sA1, bA); VMBAR();
        STAGE(4 * j + 3, 1, 3); QKT(0, sA0, sA1, bA); SMPV(1, sB0, sB1, bB); VMBAR();
        STAGE(4 * j + 4, 0, 0); QKT(1, sB0, sB1, bB); SMPV(2, sA0, sA1, bA); VMBAR();
        STAGE(4 * j + 5, 1, 1); QKT(0, sA0, sA1, bA); SMPV(3, sB0, sB1, bB); VMBAR();
    }
    // t = 61
    STAGE(62, 0, 2); QKT(1, sB0, sB1, bB); SMPV(0, sA0, sA1, bA); VMBAR();
    // t = 62
    STAGE(63, 1, 3); QKT(0, sA0, sA1, bA); SMPV(1, sB0, sB1, bB); VMBAR();
    // t = 63
    QKT(1, sB0, sB1, bB); SMPV(2, sA0, sA1, bA);
    SMPV(3, sB0, sB1, bB);

    // ---- epilogue: O^T/l -> aout [b][s][c] bf16 ----
    float inv = 1.f / sacc[0];
    int b = bh >> 2, h = bh & 3;
    short* ob = aout + ((size_t)b * SLEN + q0 + q32) * CIN + h * HD;
#pragma unroll
    for (int g4 = 0; g4 < 4; ++g4) {
        uint2 st0, st1;
        st0.x = cvt_pk(oacc0[4 * g4 + 0] * inv, oacc0[4 * g4 + 1] * inv);
        st0.y = cvt_pk(oacc0[4 * g4 + 2] * inv, oacc0[4 * g4 + 3] * inv);
        st1.x = cvt_pk(oacc1[4 * g4 + 0] * inv, oacc1[4 * g4 + 1] * inv);
        st1.y = cvt_pk(oacc1[4 * g4 + 2] * inv, oacc1[4 * g4 + 3] * inv);
        *(uint2*)(ob + 8 * g4 + 4 * hi) = st0;
        *(uint2*)(ob + 32 + 8 * g4 + 4 * hi) = st1;
    }
#undef STAGE
#undef VMBAR
#undef QKT
#undef PVKC
#undef SMPV
}

// ---------------- kernel C: proj GEMM + BN + SiLU -> fp32 out ----------------
__launch_bounds__(256)
__global__ void k_proj(const short* __restrict__ aout, const short* __restrict__ wbf,
                       const float* __restrict__ g, const float* __restrict__ be,
                       const float* __restrict__ mu, const float* __restrict__ va,
                       float* __restrict__ out) {
    int wv = threadIdx.x >> 6, l = threadIdx.x & 63, lr = l & 15, lg = l >> 4;
    int b = blockIdx.z;
    int s0 = blockIdx.x * 128 + wv * 32;
    int o0 = blockIdx.y * 64;
    f32x4 acc[2][4] = {};
    const short* aptr = aout + ((size_t)b * SLEN + s0 + lr) * CIN + lg * 8;
    const short* bptr = wbf + (size_t)(o0 + lr) * CIN + lg * 8;
#pragma unroll
    for (int k0 = 0; k0 < CIN; k0 += 32) {
        bf16x8 a0 = *(const bf16x8*)(aptr + k0);
        bf16x8 a1 = *(const bf16x8*)(aptr + 16 * CIN + k0);
#pragma unroll
        for (int oj = 0; oj < 4; oj++) {
            bf16x8 bb = *(const bf16x8*)(bptr + oj * 16 * CIN + k0);
            acc[0][oj] = __builtin_amdgcn_mfma_f32_16x16x32_bf16(a0, bb, acc[0][oj], 0, 0, 0);
            acc[1][oj] = __builtin_amdgcn_mfma_f32_16x16x32_bf16(a1, bb, acc[1][oj], 0, 0, 0);
        }
    }
#pragma unroll
    for (int oj = 0; oj < 4; oj++) {
        int o = o0 + oj * 16 + lr;
        float sc = g[o] * rsqrtf(va[o] + 1e-5f);
        float sh = be[o] - mu[o] * sc;
#pragma unroll
        for (int qi = 0; qi < 2; qi++) {
            float4 st;
            float* stp = &st.x;
#pragma unroll
            for (int i = 0; i < 4; i++) {
                float y = acc[qi][oj][i] * sc + sh;
                stp[i] = y / (1.f + __expf(-y));
            }
            int s = s0 + qi * 16 + lg * 4;
            *reinterpret_cast<float4*>(out + ((size_t)b * CIN + o) * SLEN + s) = st;
        }
    }
}

extern "C" void kernel_launch(void* const* d_in, const int* in_sizes, int n_in,
                              void* d_out, int out_size, void* d_ws, size_t ws_size,
                              hipStream_t stream) {
    const float* x    = (const float*)d_in[0];
    const float* qkvw = (const float*)d_in[1];
    const float* qg   = (const float*)d_in[2];
    const float* qbe  = (const float*)d_in[3];
    const float* qmu  = (const float*)d_in[4];
    const float* qva  = (const float*)d_in[5];
    const float* pw   = (const float*)d_in[6];
    const float* pg   = (const float*)d_in[7];
    const float* pbe  = (const float*)d_in[8];
    const float* pmu  = (const float*)d_in[9];
    const float* pva  = (const float*)d_in[10];
    float* out = (float*)d_out;

    char* ws = (char*)d_ws;
    short* qkvw_bf  = (short*)(ws);                 //    393,216 B
    short* projw_bf = (short*)(ws + 393216);        //    131,072 B
    short* Qb       = (short*)(ws + 524288);        //  8,388,608 B
    short* Kb       = (short*)(ws + 8912896);       //  8,388,608 B
    short* Vt       = (short*)(ws + 17301504);      //  8,388,608 B
    short* aout     = (short*)(ws + 25690112);      //  8,388,608 B

    k_convert_w<<<768, 256, 0, stream>>>(qkvw, pw, qkvw_bf, projw_bf);
    k_qkv<<<dim3(32, 6, 4), 256, 0, stream>>>(x, qkvw_bf, qg, qbe, qmu, qva, Qb, Kb, Vt);
    k_attn<<<512, 256, 0, stream>>>(Qb, Kb, Vt, aout);
    k_proj<<<dim3(32, 4, 4), 256, 0, stream>>>(aout, projw_bf, pg, pbe, pmu, pva, out);
}

// Round 15
// 152.981 us; speedup vs baseline: 5.9188x; 1.0212x over previous
//
#include <hip/hip_runtime.h>
#include <hip/hip_bf16.h>
#include <math.h>

#define SLEN 4096
#define CIN 256
#define C3 768
#define NH 4
#define HD 64
#define BATCH 4

typedef __attribute__((ext_vector_type(8))) short bf16x8;
typedef __attribute__((ext_vector_type(4))) float f32x4;
typedef __attribute__((ext_vector_type(16))) float f32x16;

typedef const __attribute__((address_space(1))) void GVoid;
typedef __attribute__((address_space(3))) void LVoid;

__device__ __forceinline__ void gl2lds16(const void* g, void* l) {
    __builtin_amdgcn_global_load_lds((GVoid*)g, (LVoid*)l, 16, 0, 0);
}

__device__ __forceinline__ short f2bf(float f) {
    union { float f; unsigned u; } v; v.f = f;
    unsigned r = v.u + 0x7fff + ((v.u >> 16) & 1);
    return (short)(r >> 16);
}

// single-instruction packed f32->bf16 (RNE) — no builtin on gfx950, inline asm per T12
__device__ __forceinline__ unsigned cvt_pk(float lo, float hi) {
    unsigned r;
    asm("v_cvt_pk_bf16_f32 %0, %1, %2" : "=v"(r) : "v"(lo), "v"(hi));
    return r;
}

// ---------------- kernel W: convert weights to bf16 ----------------
__global__ void k_convert_w(const float* __restrict__ qkvw, const float* __restrict__ projw,
                            short* __restrict__ qkvw_bf, short* __restrict__ projw_bf) {
    int i = blockIdx.x * 256 + threadIdx.x;
    if (i < C3 * CIN) qkvw_bf[i] = f2bf(qkvw[i]);
    if (i < CIN * CIN) projw_bf[i] = f2bf(projw[i]);
}

// ---------------- kernel A: QKV GEMM + BN + SiLU, DIRECT transposed x loads ----------
// No LDS, no barriers: lane (lr,lg) loads its 8 A-frag elements straight from
// x [b][c][s] fp32 (lanes lr=0..15 per lg group cover 64B contiguous; L2-resident
// after first o-block pass). Replaces the 16-barrier LDS-transpose version.
// Q,K: [bh][s][d]; Vt: [bh][d][s]. Q pre-scaled by hd^-0.5 * log2(e).
__launch_bounds__(256)
__global__ void k_qkv(const float* __restrict__ x, const short* __restrict__ wbf,
                      const float* __restrict__ g, const float* __restrict__ be,
                      const float* __restrict__ mu, const float* __restrict__ va,
                      short* __restrict__ Q, short* __restrict__ Kb, short* __restrict__ Vt) {
    int wv = threadIdx.x >> 6, l = threadIdx.x & 63, lr = l & 15, lg = l >> 4;
    int b = blockIdx.z;
    int sblk = blockIdx.x * 128;
    int s0 = sblk + wv * 32;
    int o0 = blockIdx.y * 64;

    f32x4 acc[2][4] = {};
    const short* bptr = wbf + (size_t)(o0 + lr) * CIN + lg * 8;
    // lane's x base: k-row (lg*8), s-col (s0 + lr); k-row stride = SLEN floats
    const float* x0 = x + (size_t)b * CIN * SLEN + (size_t)(lg * 8) * SLEN + s0 + lr;

#pragma unroll
    for (int ch = 0; ch < 8; ++ch) {
        const float* xc = x0 + (size_t)ch * 32 * SLEN;
        union { bf16x8 v; unsigned u[4]; } a0, a1;
#pragma unroll
        for (int p = 0; p < 4; ++p) {
            float e0 = xc[(size_t)(2 * p) * SLEN];
            float e1 = xc[(size_t)(2 * p + 1) * SLEN];
            float f0 = xc[(size_t)(2 * p) * SLEN + 16];
            float f1 = xc[(size_t)(2 * p + 1) * SLEN + 16];
            a0.u[p] = cvt_pk(e0, e1);
            a1.u[p] = cvt_pk(f0, f1);
        }
        int k0 = ch * 32;
#pragma unroll
        for (int oj = 0; oj < 4; oj++) {
            bf16x8 bb = *(const bf16x8*)(bptr + oj * 16 * CIN + k0);
            acc[0][oj] = __builtin_amdgcn_mfma_f32_16x16x32_bf16(a0.v, bb, acc[0][oj], 0, 0, 0);
            acc[1][oj] = __builtin_amdgcn_mfma_f32_16x16x32_bf16(a1.v, bb, acc[1][oj], 0, 0, 0);
        }
    }

    int which = o0 >> 8;          // uniform per block
    int h = (o0 & 255) >> 6;      // uniform per block
    int bh = b * NH + h;
    const float QSC = 0.125f * 1.44269504088896f;
#pragma unroll
    for (int oj = 0; oj < 4; oj++) {
        int o = o0 + oj * 16 + lr;
        float sc = g[o] * rsqrtf(va[o] + 1e-5f);
        float sh = be[o] - mu[o] * sc;
        int d = o & 63;
#pragma unroll
        for (int qi = 0; qi < 2; qi++) {
#pragma unroll
            for (int i = 0; i < 4; i++) {
                float y = acc[qi][oj][i] * sc + sh;
                float z = y / (1.f + __expf(-y));
                int s = s0 + qi * 16 + lg * 4 + i;
                if (which == 0) {
                    Q[((size_t)bh * SLEN + s) * HD + d] = f2bf(z * QSC);
                } else if (which == 1) {
                    Kb[((size_t)bh * SLEN + s) * HD + d] = f2bf(z);
                } else {
                    Vt[((size_t)bh * HD + d) * SLEN + s] = f2bf(z);
                }
            }
        }
    }
}

// ---------------- kernel ATTN: flash attention, pipelined swapped-QK^T ----
// (round-6/9 structure, best measured: 95.2 us — register-equilibrium design)
// 4 waves/block, 32 q-rows/wave, KVBLK=64. K 2-buf @ lds+0, V 4-buf @ lds+16384.
// Staging via global_load_lds width=16: linear LDS dest + PRE-SWIZZLED per-lane global
// source. One vmcnt(0)+barrier per tile. XCD-aware decode: XCD k owns bh {2k,2k+1}.
// S^T = mfma_32x32x16(K, Q): lane holds 32 P values for q = lane&31.
__launch_bounds__(256, 2)
__global__ void k_attn(const short* __restrict__ Q, const short* __restrict__ Kg,
                       const short* __restrict__ Vg, short* __restrict__ aout) {
    __shared__ __align__(16) char lds[16384 + 32768];
    int tid = threadIdx.x;
    int wv = tid >> 6, l = tid & 63;
    int q32 = l & 31;
    int hi  = l >> 5;

    int bid = blockIdx.x;
    int xcd = bid & 7, slot = bid >> 3;
    int bh = 2 * xcd + (slot & 1);
    int q0 = (slot >> 1) * 128 + wv * 32;

    const short* kg = Kg + (size_t)bh * SLEN * HD;
    const short* vg = Vg + (size_t)bh * HD * SLEN;

    bf16x8 qf[4];
    {
        const short* qb = Q + ((size_t)bh * SLEN + q0 + q32) * HD + hi * 8;
        qf[0] = *(const bf16x8*)(qb);
        qf[1] = *(const bf16x8*)(qb + 16);
        qf[2] = *(const bf16x8*)(qb + 32);
        qf[3] = *(const bf16x8*)(qb + 48);
    }

    bf16x8 ones;
#pragma unroll
    for (int e = 0; e < 8; ++e) ones[e] = (short)0x3F80;

    f32x16 oacc0 = {}, oacc1 = {}, sacc = {};
    float mrun = 0.0f, bA = 0.0f, bB = 0.0f;

    int colsw = (((l & 7) ^ (l >> 3)) << 4);
    const char* kgB = (const char*)kg;
    const char* vgB = (const char*)vg;
    int ksrc = (wv * 16 + (l >> 3)) * 128 + colsw;
    int vsrc = (wv * 16 + (l >> 3)) * 8192 + colsw;
    int wdst = wv * 2048;

#define STAGE(T, KB, VB) do { \
    gl2lds16(kgB + (size_t)(T) * 8192 + ksrc,          lds + (KB) * 8192 + wdst); \
    gl2lds16(kgB + (size_t)(T) * 8192 + ksrc + 1024,   lds + (KB) * 8192 + wdst + 1024); \
    gl2lds16(vgB + (size_t)(T) * 128 + vsrc,           lds + 16384 + (VB) * 8192 + wdst); \
    gl2lds16(vgB + (size_t)(T) * 128 + vsrc + 65536,   lds + 16384 + (VB) * 8192 + wdst + 1024); \
} while (0)

#define VMBAR() do { \
    asm volatile("s_waitcnt vmcnt(0) lgkmcnt(0)" ::: "memory"); \
    __builtin_amdgcn_s_barrier(); \
    asm volatile("" ::: "memory"); \
} while (0)

    int swz = (l & 7) << 4;
    int a0 = q32 * 128 + ((0 * 32 + hi * 16) ^ swz);
    int a1 = q32 * 128 + ((1 * 32 + hi * 16) ^ swz);
    int a2 = q32 * 128 + ((2 * 32 + hi * 16) ^ swz);
    int a3 = q32 * 128 + ((3 * 32 + hi * 16) ^ swz);

#define QKT(KB, D0, D1, BSET) do { \
    BSET = mrun; \
    float nb_ = -mrun; \
    _Pragma("unroll") for (int r_ = 0; r_ < 16; ++r_) { D0[r_] = nb_; D1[r_] = nb_; } \
    __builtin_amdgcn_s_setprio(1); \
    { \
        bf16x8 k0_, k1_; \
        k0_ = *(const bf16x8*)(lds + a0 + (KB) * 8192); \
        k1_ = *(const bf16x8*)(lds + a0 + (KB) * 8192 + 4096); \
        D0 = __builtin_amdgcn_mfma_f32_32x32x16_bf16(k0_, qf[0], D0, 0, 0, 0); \
        D1 = __builtin_amdgcn_mfma_f32_32x32x16_bf16(k1_, qf[0], D1, 0, 0, 0); \
        k0_ = *(const bf16x8*)(lds + a1 + (KB) * 8192); \
        k1_ = *(const bf16x8*)(lds + a1 + (KB) * 8192 + 4096); \
        D0 = __builtin_amdgcn_mfma_f32_32x32x16_bf16(k0_, qf[1], D0, 0, 0, 0); \
        D1 = __builtin_amdgcn_mfma_f32_32x32x16_bf16(k1_, qf[1], D1, 0, 0, 0); \
        k0_ = *(const bf16x8*)(lds + a2 + (KB) * 8192); \
        k1_ = *(const bf16x8*)(lds + a2 + (KB) * 8192 + 4096); \
        D0 = __builtin_amdgcn_mfma_f32_32x32x16_bf16(k0_, qf[2], D0, 0, 0, 0); \
        D1 = __builtin_amdgcn_mfma_f32_32x32x16_bf16(k1_, qf[2], D1, 0, 0, 0); \
        k0_ = *(const bf16x8*)(lds + a3 + (KB) * 8192); \
        k1_ = *(const bf16x8*)(lds + a3 + (KB) * 8192 + 4096); \
        D0 = __builtin_amdgcn_mfma_f32_32x32x16_bf16(k0_, qf[3], D0, 0, 0, 0); \
        D1 = __builtin_amdgcn_mfma_f32_32x32x16_bf16(k1_, qf[3], D1, 0, 0, 0); \
    } \
    __builtin_amdgcn_s_setprio(0); \
} while (0)

#define PVKC(AK, SV, BASE, VB) do { \
    unsigned A0_ = cvt_pk(SV[(BASE) + 0], SV[(BASE) + 1]); \
    unsigned A1_ = cvt_pk(SV[(BASE) + 2], SV[(BASE) + 3]); \
    unsigned A2_ = cvt_pk(SV[(BASE) + 4], SV[(BASE) + 5]); \
    unsigned A3_ = cvt_pk(SV[(BASE) + 6], SV[(BASE) + 7]); \
    asm volatile("v_permlane32_swap_b32 %0, %1" : "+v"(A0_), "+v"(A2_)); \
    asm volatile("v_permlane32_swap_b32 %0, %1" : "+v"(A1_), "+v"(A3_)); \
    union { bf16x8 v; unsigned u[4]; } pf_; \
    pf_.u[0] = A0_; pf_.u[1] = A1_; pf_.u[2] = A2_; pf_.u[3] = A3_; \
    bf16x8 v0_ = *(const bf16x8*)(lds + (AK) + 16384 + (VB) * 8192); \
    bf16x8 v1_ = *(const bf16x8*)(lds + (AK) + 16384 + (VB) * 8192 + 4096); \
    oacc0 = __builtin_amdgcn_mfma_f32_32x32x16_bf16(v0_, pf_.v, oacc0, 0, 0, 0); \
    oacc1 = __builtin_amdgcn_mfma_f32_32x32x16_bf16(v1_, pf_.v, oacc1, 0, 0, 0); \
    sacc  = __builtin_amdgcn_mfma_f32_32x32x16_bf16(ones, pf_.v, sacc, 0, 0, 0); \
} while (0)

#define SMPV(VB, S0, S1, BSET) do { \
    float pa_ = S0[0], pb_ = S0[8], pc_ = S1[0], pd_ = S1[8]; \
    _Pragma("unroll") for (int r_ = 1; r_ < 8; ++r_) { \
        pa_ = fmaxf(pa_, S0[r_]); pb_ = fmaxf(pb_, S0[8 + r_]); \
        pc_ = fmaxf(pc_, S1[r_]); pd_ = fmaxf(pd_, S1[8 + r_]); \
    } \
    float pms_ = fmaxf(fmaxf(pa_, pb_), fmaxf(pc_, pd_)); \
    float c1_ = pms_, c2_ = pms_; \
    asm volatile("" : "+v"(c2_)); /* force distinct register */ \
    asm volatile("v_permlane32_swap_b32 %0, %1" : "+v"(c1_), "+v"(c2_)); \
    pms_ = fmaxf(c1_, c2_); \
    float db_ = mrun - (BSET); \
    if (!__all(pms_ <= db_ + 10.0f)) { \
        float mn_ = fmaxf(mrun, pms_ + (BSET)); \
        float al_ = __builtin_amdgcn_exp2f(mrun - mn_); \
        _Pragma("unroll") for (int r_ = 0; r_ < 16; ++r_) { oacc0[r_] *= al_; oacc1[r_] *= al_; } \
        sacc[0] *= al_; \
        mrun = mn_; db_ = mn_ - (BSET); \
    } \
    if (__all(db_ == 0.0f)) { \
        _Pragma("unroll") for (int r_ = 0; r_ < 16; ++r_) { \
            S0[r_] = __builtin_amdgcn_exp2f(S0[r_]); \
            S1[r_] = __builtin_amdgcn_exp2f(S1[r_]); \
        } \
    } else { \
        _Pragma("unroll") for (int r_ = 0; r_ < 16; ++r_) { \
            S0[r_] = __builtin_amdgcn_exp2f(S0[r_] - db_); \
            S1[r_] = __builtin_amdgcn_exp2f(S1[r_] - db_); \
        } \
    } \
    __builtin_amdgcn_s_setprio(1); \
    PVKC(a0, S0, 0, VB); \
    PVKC(a1, S0, 8, VB); \
    PVKC(a2, S1, 0, VB); \
    PVKC(a3, S1, 8, VB); \
    __builtin_amdgcn_s_setprio(0); \
} while (0)

    f32x16 sA0, sA1, sB0, sB1;

    // prologue: stage 0; drain; stage 1 + QK(0); drain
    STAGE(0, 0, 0);
    VMBAR();
    STAGE(1, 1, 1);
    QKT(0, sA0, sA1, bA);
    VMBAR();

    // steady state: tiles 1..60, unroll 4 (all buffer indices literal)
    for (int j = 0; j < 15; ++j) {
        STAGE(4 * j + 2, 0, 2); QKT(1, sB0, sB1, bB); SMPV(0, sA0, sA1, bA); VMBAR();
        STAGE(4 * j + 3, 1, 3); QKT(0, sA0, sA1, bA); SMPV(1, sB0, sB1, bB); VMBAR();
        STAGE(4 * j + 4, 0, 0); QKT(1, sB0, sB1, bB); SMPV(2, sA0, sA1, bA); VMBAR();
        STAGE(4 * j + 5, 1, 1); QKT(0, sA0, sA1, bA); SMPV(3, sB0, sB1, bB); VMBAR();
    }
    // t = 61
    STAGE(62, 0, 2); QKT(1, sB0, sB1, bB); SMPV(0, sA0, sA1, bA); VMBAR();
    // t = 62
    STAGE(63, 1, 3); QKT(0, sA0, sA1, bA); SMPV(1, sB0, sB1, bB); VMBAR();
    // t = 63
    QKT(1, sB0, sB1, bB); SMPV(2, sA0, sA1, bA);
    SMPV(3, sB0, sB1, bB);

    // ---- epilogue: O^T/l -> aout [b][s][c] bf16 ----
    float inv = 1.f / sacc[0];
    int b = bh >> 2, h = bh & 3;
    short* ob = aout + ((size_t)b * SLEN + q0 + q32) * CIN + h * HD;
#pragma unroll
    for (int g4 = 0; g4 < 4; ++g4) {
        uint2 st0, st1;
        st0.x = cvt_pk(oacc0[4 * g4 + 0] * inv, oacc0[4 * g4 + 1] * inv);
        st0.y = cvt_pk(oacc0[4 * g4 + 2] * inv, oacc0[4 * g4 + 3] * inv);
        st1.x = cvt_pk(oacc1[4 * g4 + 0] * inv, oacc1[4 * g4 + 1] * inv);
        st1.y = cvt_pk(oacc1[4 * g4 + 2] * inv, oacc1[4 * g4 + 3] * inv);
        *(uint2*)(ob + 8 * g4 + 4 * hi) = st0;
        *(uint2*)(ob + 32 + 8 * g4 + 4 * hi) = st1;
    }
#undef STAGE
#undef VMBAR
#undef QKT
#undef PVKC
#undef SMPV
}

// ---------------- kernel C: proj GEMM + BN + SiLU -> fp32 out ----------------
__launch_bounds__(256)
__global__ void k_proj(const short* __restrict__ aout, const short* __restrict__ wbf,
                       const float* __restrict__ g, const float* __restrict__ be,
                       const float* __restrict__ mu, const float* __restrict__ va,
                       float* __restrict__ out) {
    int wv = threadIdx.x >> 6, l = threadIdx.x & 63, lr = l & 15, lg = l >> 4;
    int b = blockIdx.z;
    int s0 = blockIdx.x * 128 + wv * 32;
    int o0 = blockIdx.y * 64;
    f32x4 acc[2][4] = {};
    const short* aptr = aout + ((size_t)b * SLEN + s0 + lr) * CIN + lg * 8;
    const short* bptr = wbf + (size_t)(o0 + lr) * CIN + lg * 8;
#pragma unroll
    for (int k0 = 0; k0 < CIN; k0 += 32) {
        bf16x8 a0 = *(const bf16x8*)(aptr + k0);
        bf16x8 a1 = *(const bf16x8*)(aptr + 16 * CIN + k0);
#pragma unroll
        for (int oj = 0; oj < 4; oj++) {
            bf16x8 bb = *(const bf16x8*)(bptr + oj * 16 * CIN + k0);
            acc[0][oj] = __builtin_amdgcn_mfma_f32_16x16x32_bf16(a0, bb, acc[0][oj], 0, 0, 0);
            acc[1][oj] = __builtin_amdgcn_mfma_f32_16x16x32_bf16(a1, bb, acc[1][oj], 0, 0, 0);
        }
    }
#pragma unroll
    for (int oj = 0; oj < 4; oj++) {
        int o = o0 + oj * 16 + lr;
        float sc = g[o] * rsqrtf(va[o] + 1e-5f);
        float sh = be[o] - mu[o] * sc;
#pragma unroll
        for (int qi = 0; qi < 2; qi++) {
            float4 st;
            float* stp = &st.x;
#pragma unroll
            for (int i = 0; i < 4; i++) {
                float y = acc[qi][oj][i] * sc + sh;
                stp[i] = y / (1.f + __expf(-y));
            }
            int s = s0 + qi * 16 + lg * 4;
            *reinterpret_cast<float4*>(out + ((size_t)b * CIN + o) * SLEN + s) = st;
        }
    }
}

extern "C" void kernel_launch(void* const* d_in, const int* in_sizes, int n_in,
                              void* d_out, int out_size, void* d_ws, size_t ws_size,
                              hipStream_t stream) {
    const float* x    = (const float*)d_in[0];
    const float* qkvw = (const float*)d_in[1];
    const float* qg   = (const float*)d_in[2];
    const float* qbe  = (const float*)d_in[3];
    const float* qmu  = (const float*)d_in[4];
    const float* qva  = (const float*)d_in[5];
    const float* pw   = (const float*)d_in[6];
    const float* pg   = (const float*)d_in[7];
    const float* pbe  = (const float*)d_in[8];
    const float* pmu  = (const float*)d_in[9];
    const float* pva  = (const float*)d_in[10];
    float* out = (float*)d_out;

    char* ws = (char*)d_ws;
    short* qkvw_bf  = (short*)(ws);                 //    393,216 B
    short* projw_bf = (short*)(ws + 393216);        //    131,072 B
    short* Qb       = (short*)(ws + 524288);        //  8,388,608 B
    short* Kb       = (short*)(ws + 8912896);       //  8,388,608 B
    short* Vt       = (short*)(ws + 17301504);      //  8,388,608 B
    short* aout     = (short*)(ws + 25690112);      //  8,388,608 B

    k_convert_w<<<768, 256, 0, stream>>>(qkvw, pw, qkvw_bf, projw_bf);
    k_qkv<<<dim3(32, 12, 4), 256, 0, stream>>>(x, qkvw_bf, qg, qbe, qmu, qva, Qb, Kb, Vt);
    k_attn<<<512, 256, 0, stream>>>(Qb, Kb, Vt, aout);
    k_proj<<<dim3(32, 4, 4), 256, 0, stream>>>(aout, projw_bf, pg, pbe, pmu, pva, out);
}

// Round 16
// 152.853 us; speedup vs baseline: 5.9237x; 1.0008x over previous
//
#include <hip/hip_runtime.h>
#include <hip/hip_bf16.h>
#include <math.h>

#define SLEN 4096
#define CIN 256
#define C3 768
#define NH 4
#define HD 64
#define BATCH 4

typedef __attribute__((ext_vector_type(8))) short bf16x8;
typedef __attribute__((ext_vector_type(4))) float f32x4;
typedef __attribute__((ext_vector_type(16))) float f32x16;

typedef const __attribute__((address_space(1))) void GVoid;
typedef __attribute__((address_space(3))) void LVoid;

__device__ __forceinline__ void gl2lds16(const void* g, void* l) {
    __builtin_amdgcn_global_load_lds((GVoid*)g, (LVoid*)l, 16, 0, 0);
}

__device__ __forceinline__ short f2bf(float f) {
    union { float f; unsigned u; } v; v.f = f;
    unsigned r = v.u + 0x7fff + ((v.u >> 16) & 1);
    return (short)(r >> 16);
}

// single-instruction packed f32->bf16 (RNE) — no builtin on gfx950, inline asm per T12
__device__ __forceinline__ unsigned cvt_pk(float lo, float hi) {
    unsigned r;
    asm("v_cvt_pk_bf16_f32 %0, %1, %2" : "=v"(r) : "v"(lo), "v"(hi));
    return r;
}

// ---------------- kernel W: convert weights to bf16 ----------------
__global__ void k_convert_w(const float* __restrict__ qkvw, const float* __restrict__ projw,
                            short* __restrict__ qkvw_bf, short* __restrict__ projw_bf) {
    int i = blockIdx.x * 256 + threadIdx.x;
    if (i < C3 * CIN) qkvw_bf[i] = f2bf(qkvw[i]);
    if (i < CIN * CIN) projw_bf[i] = f2bf(projw[i]);
}

// ---------------- kernel A: QKV GEMM + BN + SiLU, DIRECT transposed x loads ----------
// No LDS, no barriers: lane (lr,lg) loads its 8 A-frag elements straight from
// x [b][c][s] fp32 (lanes lr=0..15 per lg group cover 64B contiguous; L2-resident
// after first o-block pass).
// Q,K: [bh][s][d]; Vt: [bh][d][s]. Q pre-scaled by hd^-0.5 * log2(e).
__launch_bounds__(256)
__global__ void k_qkv(const float* __restrict__ x, const short* __restrict__ wbf,
                      const float* __restrict__ g, const float* __restrict__ be,
                      const float* __restrict__ mu, const float* __restrict__ va,
                      short* __restrict__ Q, short* __restrict__ Kb, short* __restrict__ Vt) {
    int wv = threadIdx.x >> 6, l = threadIdx.x & 63, lr = l & 15, lg = l >> 4;
    int b = blockIdx.z;
    int sblk = blockIdx.x * 128;
    int s0 = sblk + wv * 32;
    int o0 = blockIdx.y * 64;

    f32x4 acc[2][4] = {};
    const short* bptr = wbf + (size_t)(o0 + lr) * CIN + lg * 8;
    // lane's x base: k-row (lg*8), s-col (s0 + lr); k-row stride = SLEN floats
    const float* x0 = x + (size_t)b * CIN * SLEN + (size_t)(lg * 8) * SLEN + s0 + lr;

#pragma unroll
    for (int ch = 0; ch < 8; ++ch) {
        const float* xc = x0 + (size_t)ch * 32 * SLEN;
        union { bf16x8 v; unsigned u[4]; } a0, a1;
#pragma unroll
        for (int p = 0; p < 4; ++p) {
            float e0 = xc[(size_t)(2 * p) * SLEN];
            float e1 = xc[(size_t)(2 * p + 1) * SLEN];
            float f0 = xc[(size_t)(2 * p) * SLEN + 16];
            float f1 = xc[(size_t)(2 * p + 1) * SLEN + 16];
            a0.u[p] = cvt_pk(e0, e1);
            a1.u[p] = cvt_pk(f0, f1);
        }
        int k0 = ch * 32;
#pragma unroll
        for (int oj = 0; oj < 4; oj++) {
            bf16x8 bb = *(const bf16x8*)(bptr + oj * 16 * CIN + k0);
            acc[0][oj] = __builtin_amdgcn_mfma_f32_16x16x32_bf16(a0.v, bb, acc[0][oj], 0, 0, 0);
            acc[1][oj] = __builtin_amdgcn_mfma_f32_16x16x32_bf16(a1.v, bb, acc[1][oj], 0, 0, 0);
        }
    }

    int which = o0 >> 8;          // uniform per block
    int h = (o0 & 255) >> 6;      // uniform per block
    int bh = b * NH + h;
    const float QSC = 0.125f * 1.44269504088896f;
#pragma unroll
    for (int oj = 0; oj < 4; oj++) {
        int o = o0 + oj * 16 + lr;
        float sc = g[o] * rsqrtf(va[o] + 1e-5f);
        float sh = be[o] - mu[o] * sc;
        int d = o & 63;
#pragma unroll
        for (int qi = 0; qi < 2; qi++) {
#pragma unroll
            for (int i = 0; i < 4; i++) {
                float y = acc[qi][oj][i] * sc + sh;
                float z = y / (1.f + __expf(-y));
                int s = s0 + qi * 16 + lg * 4 + i;
                if (which == 0) {
                    Q[((size_t)bh * SLEN + s) * HD + d] = f2bf(z * QSC);
                } else if (which == 1) {
                    Kb[((size_t)bh * SLEN + s) * HD + d] = f2bf(z);
                } else {
                    Vt[((size_t)bh * HD + d) * SLEN + s] = f2bf(z);
                }
            }
        }
    }
}

// ---------------- kernel ATTN: flash attention, T4 counted-vmcnt pipeline ----
// r6/r9 structure + pipeline depth 2: stage tile t+2 during phase t; phase boundary
// waits vmcnt(4) ONLY (the 4 just-issued loads stay in flight across the barrier).
// K 4-buf @ lds+0, V 4-buf @ lds+32768 (65536 B -> 2 blocks/CU). Buffer t&3;
// phase t reads K[t&3], V[(t-1)&3], writes [(t+2)&3] — distinct mod 4.
// S^T = mfma_32x32x16(K, Q): lane holds 32 P values for q = lane&31.
__launch_bounds__(256, 2)
__global__ void k_attn(const short* __restrict__ Q, const short* __restrict__ Kg,
                       const short* __restrict__ Vg, short* __restrict__ aout) {
    __shared__ __align__(16) char lds[32768 + 32768];
    int tid = threadIdx.x;
    int wv = tid >> 6, l = tid & 63;
    int q32 = l & 31;
    int hi  = l >> 5;

    int bid = blockIdx.x;
    int xcd = bid & 7, slot = bid >> 3;
    int bh = 2 * xcd + (slot & 1);
    int q0 = (slot >> 1) * 128 + wv * 32;

    const short* kg = Kg + (size_t)bh * SLEN * HD;
    const short* vg = Vg + (size_t)bh * HD * SLEN;

    bf16x8 qf[4];
    {
        const short* qb = Q + ((size_t)bh * SLEN + q0 + q32) * HD + hi * 8;
        qf[0] = *(const bf16x8*)(qb);
        qf[1] = *(const bf16x8*)(qb + 16);
        qf[2] = *(const bf16x8*)(qb + 32);
        qf[3] = *(const bf16x8*)(qb + 48);
    }

    bf16x8 ones;
#pragma unroll
    for (int e = 0; e < 8; ++e) ones[e] = (short)0x3F80;

    f32x16 oacc0 = {}, oacc1 = {}, sacc = {};
    float mrun = 0.0f, bA = 0.0f, bB = 0.0f;

    int colsw = (((l & 7) ^ (l >> 3)) << 4);
    const char* kgB = (const char*)kg;
    const char* vgB = (const char*)vg;
    int ksrc = (wv * 16 + (l >> 3)) * 128 + colsw;
    int vsrc = (wv * 16 + (l >> 3)) * 8192 + colsw;
    int wdst = wv * 2048;

#define STAGE(T, B) do { \
    gl2lds16(kgB + (size_t)(T) * 8192 + ksrc,          lds + (B) * 8192 + wdst); \
    gl2lds16(kgB + (size_t)(T) * 8192 + ksrc + 1024,   lds + (B) * 8192 + wdst + 1024); \
    gl2lds16(vgB + (size_t)(T) * 128 + vsrc,           lds + 32768 + (B) * 8192 + wdst); \
    gl2lds16(vgB + (size_t)(T) * 128 + vsrc + 65536,   lds + 32768 + (B) * 8192 + wdst + 1024); \
} while (0)

// counted-vmcnt phase boundary: the 4 loads issued THIS phase stay in flight
#define VMBAR4() do { \
    asm volatile("s_waitcnt vmcnt(4) lgkmcnt(0)" ::: "memory"); \
    __builtin_amdgcn_s_barrier(); \
    asm volatile("" ::: "memory"); \
} while (0)

#define VMBAR0() do { \
    asm volatile("s_waitcnt vmcnt(0) lgkmcnt(0)" ::: "memory"); \
    __builtin_amdgcn_s_barrier(); \
    asm volatile("" ::: "memory"); \
} while (0)

    int swz = (l & 7) << 4;
    int a0 = q32 * 128 + ((0 * 32 + hi * 16) ^ swz);
    int a1 = q32 * 128 + ((1 * 32 + hi * 16) ^ swz);
    int a2 = q32 * 128 + ((2 * 32 + hi * 16) ^ swz);
    int a3 = q32 * 128 + ((3 * 32 + hi * 16) ^ swz);

#define QKT(KB, D0, D1, BSET) do { \
    BSET = mrun; \
    float nb_ = -mrun; \
    _Pragma("unroll") for (int r_ = 0; r_ < 16; ++r_) { D0[r_] = nb_; D1[r_] = nb_; } \
    __builtin_amdgcn_s_setprio(1); \
    { \
        bf16x8 k0_, k1_; \
        k0_ = *(const bf16x8*)(lds + a0 + (KB) * 8192); \
        k1_ = *(const bf16x8*)(lds + a0 + (KB) * 8192 + 4096); \
        D0 = __builtin_amdgcn_mfma_f32_32x32x16_bf16(k0_, qf[0], D0, 0, 0, 0); \
        D1 = __builtin_amdgcn_mfma_f32_32x32x16_bf16(k1_, qf[0], D1, 0, 0, 0); \
        k0_ = *(const bf16x8*)(lds + a1 + (KB) * 8192); \
        k1_ = *(const bf16x8*)(lds + a1 + (KB) * 8192 + 4096); \
        D0 = __builtin_amdgcn_mfma_f32_32x32x16_bf16(k0_, qf[1], D0, 0, 0, 0); \
        D1 = __builtin_amdgcn_mfma_f32_32x32x16_bf16(k1_, qf[1], D1, 0, 0, 0); \
        k0_ = *(const bf16x8*)(lds + a2 + (KB) * 8192); \
        k1_ = *(const bf16x8*)(lds + a2 + (KB) * 8192 + 4096); \
        D0 = __builtin_amdgcn_mfma_f32_32x32x16_bf16(k0_, qf[2], D0, 0, 0, 0); \
        D1 = __builtin_amdgcn_mfma_f32_32x32x16_bf16(k1_, qf[2], D1, 0, 0, 0); \
        k0_ = *(const bf16x8*)(lds + a3 + (KB) * 8192); \
        k1_ = *(const bf16x8*)(lds + a3 + (KB) * 8192 + 4096); \
        D0 = __builtin_amdgcn_mfma_f32_32x32x16_bf16(k0_, qf[3], D0, 0, 0, 0); \
        D1 = __builtin_amdgcn_mfma_f32_32x32x16_bf16(k1_, qf[3], D1, 0, 0, 0); \
    } \
    __builtin_amdgcn_s_setprio(0); \
} while (0)

#define PVKC(AK, SV, BASE, VB) do { \
    unsigned A0_ = cvt_pk(SV[(BASE) + 0], SV[(BASE) + 1]); \
    unsigned A1_ = cvt_pk(SV[(BASE) + 2], SV[(BASE) + 3]); \
    unsigned A2_ = cvt_pk(SV[(BASE) + 4], SV[(BASE) + 5]); \
    unsigned A3_ = cvt_pk(SV[(BASE) + 6], SV[(BASE) + 7]); \
    asm volatile("v_permlane32_swap_b32 %0, %1" : "+v"(A0_), "+v"(A2_)); \
    asm volatile("v_permlane32_swap_b32 %0, %1" : "+v"(A1_), "+v"(A3_)); \
    union { bf16x8 v; unsigned u[4]; } pf_; \
    pf_.u[0] = A0_; pf_.u[1] = A1_; pf_.u[2] = A2_; pf_.u[3] = A3_; \
    bf16x8 v0_ = *(const bf16x8*)(lds + (AK) + 32768 + (VB) * 8192); \
    bf16x8 v1_ = *(const bf16x8*)(lds + (AK) + 32768 + (VB) * 8192 + 4096); \
    oacc0 = __builtin_amdgcn_mfma_f32_32x32x16_bf16(v0_, pf_.v, oacc0, 0, 0, 0); \
    oacc1 = __builtin_amdgcn_mfma_f32_32x32x16_bf16(v1_, pf_.v, oacc1, 0, 0, 0); \
    sacc  = __builtin_amdgcn_mfma_f32_32x32x16_bf16(ones, pf_.v, sacc, 0, 0, 0); \
} while (0)

#define SMPV(VB, S0, S1, BSET) do { \
    float pa_ = S0[0], pb_ = S0[8], pc_ = S1[0], pd_ = S1[8]; \
    _Pragma("unroll") for (int r_ = 1; r_ < 8; ++r_) { \
        pa_ = fmaxf(pa_, S0[r_]); pb_ = fmaxf(pb_, S0[8 + r_]); \
        pc_ = fmaxf(pc_, S1[r_]); pd_ = fmaxf(pd_, S1[8 + r_]); \
    } \
    float pms_ = fmaxf(fmaxf(pa_, pb_), fmaxf(pc_, pd_)); \
    float c1_ = pms_, c2_ = pms_; \
    asm volatile("" : "+v"(c2_)); /* force distinct register */ \
    asm volatile("v_permlane32_swap_b32 %0, %1" : "+v"(c1_), "+v"(c2_)); \
    pms_ = fmaxf(c1_, c2_); \
    float db_ = mrun - (BSET); \
    if (!__all(pms_ <= db_ + 10.0f)) { \
        float mn_ = fmaxf(mrun, pms_ + (BSET)); \
        float al_ = __builtin_amdgcn_exp2f(mrun - mn_); \
        _Pragma("unroll") for (int r_ = 0; r_ < 16; ++r_) { oacc0[r_] *= al_; oacc1[r_] *= al_; } \
        sacc[0] *= al_; \
        mrun = mn_; db_ = mn_ - (BSET); \
    } \
    if (__all(db_ == 0.0f)) { \
        _Pragma("unroll") for (int r_ = 0; r_ < 16; ++r_) { \
            S0[r_] = __builtin_amdgcn_exp2f(S0[r_]); \
            S1[r_] = __builtin_amdgcn_exp2f(S1[r_]); \
        } \
    } else { \
        _Pragma("unroll") for (int r_ = 0; r_ < 16; ++r_) { \
            S0[r_] = __builtin_amdgcn_exp2f(S0[r_] - db_); \
            S1[r_] = __builtin_amdgcn_exp2f(S1[r_] - db_); \
        } \
    } \
    __builtin_amdgcn_s_setprio(1); \
    PVKC(a0, S0, 0, VB); \
    PVKC(a1, S0, 8, VB); \
    PVKC(a2, S1, 0, VB); \
    PVKC(a3, S1, 8, VB); \
    __builtin_amdgcn_s_setprio(0); \
} while (0)

    f32x16 sA0, sA1, sB0, sB1;

    // prologue: stage tiles 0,1; wait tile0 only (tile1 stays in flight)
    STAGE(0, 0);
    STAGE(1, 1);
    VMBAR4();
    // phase 0: stage 2; QK(0)->A
    STAGE(2, 2);
    QKT(0, sA0, sA1, bA);
    VMBAR4();
    // phase 1: stage 3; QK(1)->B; finish 0 (A)
    STAGE(3, 3);
    QKT(1, sB0, sB1, bB);
    SMPV(0, sA0, sA1, bA);
    VMBAR4();

    // steady state: phases t=2..57, unroll 4 (all buffer indices literal)
    for (int j = 0; j < 14; ++j) {
        int t = 4 * j + 2;
        STAGE(t + 2, 0); QKT(2, sA0, sA1, bA); SMPV(1, sB0, sB1, bB); VMBAR4();
        STAGE(t + 3, 1); QKT(3, sB0, sB1, bB); SMPV(2, sA0, sA1, bA); VMBAR4();
        STAGE(t + 4, 2); QKT(0, sA0, sA1, bA); SMPV(3, sB0, sB1, bB); VMBAR4();
        STAGE(t + 5, 3); QKT(1, sB0, sB1, bB); SMPV(0, sA0, sA1, bA); VMBAR4();
    }
    // t = 58
    STAGE(60, 0); QKT(2, sA0, sA1, bA); SMPV(1, sB0, sB1, bB); VMBAR4();
    // t = 59
    STAGE(61, 1); QKT(3, sB0, sB1, bB); SMPV(2, sA0, sA1, bA); VMBAR4();
    // t = 60
    STAGE(62, 2); QKT(0, sA0, sA1, bA); SMPV(3, sB0, sB1, bB); VMBAR4();
    // t = 61
    STAGE(63, 3); QKT(1, sB0, sB1, bB); SMPV(0, sA0, sA1, bA); VMBAR4();
    // t = 62 (no stage; tile 63 must land)
    QKT(2, sA0, sA1, bA); SMPV(1, sB0, sB1, bB); VMBAR0();
    // t = 63
    QKT(3, sB0, sB1, bB); SMPV(2, sA0, sA1, bA);
    SMPV(3, sB0, sB1, bB);

    // ---- epilogue: O^T/l -> aout [b][s][c] bf16 ----
    float inv = 1.f / sacc[0];
    int b = bh >> 2, h = bh & 3;
    short* ob = aout + ((size_t)b * SLEN + q0 + q32) * CIN + h * HD;
#pragma unroll
    for (int g4 = 0; g4 < 4; ++g4) {
        uint2 st0, st1;
        st0.x = cvt_pk(oacc0[4 * g4 + 0] * inv, oacc0[4 * g4 + 1] * inv);
        st0.y = cvt_pk(oacc0[4 * g4 + 2] * inv, oacc0[4 * g4 + 3] * inv);
        st1.x = cvt_pk(oacc1[4 * g4 + 0] * inv, oacc1[4 * g4 + 1] * inv);
        st1.y = cvt_pk(oacc1[4 * g4 + 2] * inv, oacc1[4 * g4 + 3] * inv);
        *(uint2*)(ob + 8 * g4 + 4 * hi) = st0;
        *(uint2*)(ob + 32 + 8 * g4 + 4 * hi) = st1;
    }
#undef STAGE
#undef VMBAR4
#undef VMBAR0
#undef QKT
#undef PVKC
#undef SMPV
}

// ---------------- kernel C: proj GEMM + BN + SiLU -> fp32 out ----------------
__launch_bounds__(256)
__global__ void k_proj(const short* __restrict__ aout, const short* __restrict__ wbf,
                       const float* __restrict__ g, const float* __restrict__ be,
                       const float* __restrict__ mu, const float* __restrict__ va,
                       float* __restrict__ out) {
    int wv = threadIdx.x >> 6, l = threadIdx.x & 63, lr = l & 15, lg = l >> 4;
    int b = blockIdx.z;
    int s0 = blockIdx.x * 128 + wv * 32;
    int o0 = blockIdx.y * 64;
    f32x4 acc[2][4] = {};
    const short* aptr = aout + ((size_t)b * SLEN + s0 + lr) * CIN + lg * 8;
    const short* bptr = wbf + (size_t)(o0 + lr) * CIN + lg * 8;
#pragma unroll
    for (int k0 = 0; k0 < CIN; k0 += 32) {
        bf16x8 a0 = *(const bf16x8*)(aptr + k0);
        bf16x8 a1 = *(const bf16x8*)(aptr + 16 * CIN + k0);
#pragma unroll
        for (int oj = 0; oj < 4; oj++) {
            bf16x8 bb = *(const bf16x8*)(bptr + oj * 16 * CIN + k0);
            acc[0][oj] = __builtin_amdgcn_mfma_f32_16x16x32_bf16(a0, bb, acc[0][oj], 0, 0, 0);
            acc[1][oj] = __builtin_amdgcn_mfma_f32_16x16x32_bf16(a1, bb, acc[1][oj], 0, 0, 0);
        }
    }
#pragma unroll
    for (int oj = 0; oj < 4; oj++) {
        int o = o0 + oj * 16 + lr;
        float sc = g[o] * rsqrtf(va[o] + 1e-5f);
        float sh = be[o] - mu[o] * sc;
#pragma unroll
        for (int qi = 0; qi < 2; qi++) {
            float4 st;
            float* stp = &st.x;
#pragma unroll
            for (int i = 0; i < 4; i++) {
                float y = acc[qi][oj][i] * sc + sh;
                stp[i] = y / (1.f + __expf(-y));
            }
            int s = s0 + qi * 16 + lg * 4;
            *reinterpret_cast<float4*>(out + ((size_t)b * CIN + o) * SLEN + s) = st;
        }
    }
}

extern "C" void kernel_launch(void* const* d_in, const int* in_sizes, int n_in,
                              void* d_out, int out_size, void* d_ws, size_t ws_size,
                              hipStream_t stream) {
    const float* x    = (const float*)d_in[0];
    const float* qkvw = (const float*)d_in[1];
    const float* qg   = (const float*)d_in[2];
    const float* qbe  = (const float*)d_in[3];
    const float* qmu  = (const float*)d_in[4];
    const float* qva  = (const float*)d_in[5];
    const float* pw   = (const float*)d_in[6];
    const float* pg   = (const float*)d_in[7];
    const float* pbe  = (const float*)d_in[8];
    const float* pmu  = (const float*)d_in[9];
    const float* pva  = (const float*)d_in[10];
    float* out = (float*)d_out;

    char* ws = (char*)d_ws;
    short* qkvw_bf  = (short*)(ws);                 //    393,216 B
    short* projw_bf = (short*)(ws + 393216);        //    131,072 B
    short* Qb       = (short*)(ws + 524288);        //  8,388,608 B
    short* Kb       = (short*)(ws + 8912896);       //  8,388,608 B
    short* Vt       = (short*)(ws + 17301504);      //  8,388,608 B
    short* aout     = (short*)(ws + 25690112);      //  8,388,608 B

    k_convert_w<<<768, 256, 0, stream>>>(qkvw, pw, qkvw_bf, projw_bf);
    k_qkv<<<dim3(32, 12, 4), 256, 0, stream>>>(x, qkvw_bf, qg, qbe, qmu, qva, Qb, Kb, Vt);
    k_attn<<<512, 256, 0, stream>>>(Qb, Kb, Vt, aout);
    k_proj<<<dim3(32, 4, 4), 256, 0, stream>>>(aout, projw_bf, pg, pbe, pmu, pva, out);
}